// Round 1
// baseline (4570.109 us; speedup 1.0000x reference)
//
#include <hip/hip_runtime.h>
#include <math.h>

namespace {

constexpr int Bn = 8, CINn = 16, Ln = 256, Dn = 256, Hn = 8, DKn = 32, DVn = 32;
constexpr int KWn = 3, KEn = 5, L4n = 1024;
constexpr float EPSf = 1e-9f;
constexpr int TLn = 8;

__device__ __forceinline__ float2 cmul(float2 a, float2 b){
  return make_float2(a.x*b.x - a.y*b.y, a.x*b.y + a.y*b.x);
}
__device__ __forceinline__ float2 cfma(float2 a, float2 b, float2 c){
  c.x = fmaf(a.x, b.x, c.x); c.x = fmaf(-a.y, b.y, c.x);
  c.y = fmaf(a.x, b.y, c.y); c.y = fmaf(a.y, b.x, c.y);
  return c;
}
__device__ __forceinline__ float2 c_add(float2 a, float2 b){
  return make_float2(a.x + b.x, a.y + b.y);
}

// A[b,o,l] = sum_c sum_i X[b,c,l+i-1] * hw[o,c,i] + hb[o]
__global__ void head_conv_kernel(const float2* __restrict__ X, const float2* __restrict__ hw,
                                 const float2* __restrict__ hb, float2* __restrict__ out){
  int idx = blockIdx.x * blockDim.x + threadIdx.x;
  if (idx >= Bn*Dn*Ln) return;
  int l = idx & (Ln-1);
  int o = (idx >> 8) & (Dn-1);
  int b = idx >> 16;
  float2 acc = hb[o];
  for (int c = 0; c < CINn; ++c){
    const float2* xr = X + (size_t)(b*CINn + c)*Ln;
    const float2* wr = hw + (size_t)(o*CINn + c)*KWn;
    #pragma unroll
    for (int i = 0; i < KWn; ++i){
      int ll = l + i - 1;
      if (ll >= 0 && ll < Ln) acc = cfma(xr[ll], wr[i], acc);
    }
  }
  out[idx] = acc;
}

// In-LDS radix-2 FFT, one block (256 threads) per row of N complex.
// sign = -1 forward, +1 inverse; scale applied at the end.
template<int N, int LOG>
__global__ void fft_rows_kernel(const float2* __restrict__ in, float2* __restrict__ out,
                                float sign, float scale){
  __shared__ float2 buf[N];
  int row = blockIdx.x;
  const float2* src = in + (size_t)row * N;
  int tid = threadIdx.x;
  for (int i = tid; i < N; i += 256){
    unsigned r = __brev((unsigned)i) >> (32 - LOG);
    buf[r] = src[i];
  }
  __syncthreads();
  for (int len = 2; len <= N; len <<= 1){
    int half = len >> 1;
    for (int bf = tid; bf < N/2; bf += 256){
      int blk = bf / half;
      int pos = bf - blk*half;
      int i0 = blk*len + pos;
      int i1 = i0 + half;
      float ang = sign * 6.2831853071795864f * (float)pos / (float)len;
      float s, c;
      sincosf(ang, &s, &c);
      float2 w = make_float2(c, s);
      float2 u = buf[i0];
      float2 t = cmul(w, buf[i1]);
      buf[i0] = make_float2(u.x + t.x, u.y + t.y);
      buf[i1] = make_float2(u.x - t.x, u.y - t.y);
    }
    __syncthreads();
  }
  float2* dst = out + (size_t)row * N;
  for (int i = tid; i < N; i += 256)
    dst[i] = make_float2(buf[i].x * scale, buf[i].y * scale);
}

// Q[b,l,e] = sum_d Ain[b,d,l] * W[d,e]   (Ain stored [B,D,L], i.e. we use its transpose)
// Block: one b, TLn consecutive l values; thread = e.
__global__ void proj_kernel(const float2* __restrict__ Ain, const float2* __restrict__ W,
                            float2* __restrict__ Q){
  __shared__ float2 Ash[Dn*TLn];   // Ash[d*TLn + t] = Ain[b,d,l0+t]
  int b = blockIdx.x / (Ln/TLn);
  int l0 = (blockIdx.x % (Ln/TLn)) * TLn;
  int tid = threadIdx.x;
  for (int j = tid; j < Dn*TLn; j += 256){
    int d = j >> 3, t = j & (TLn-1);
    Ash[j] = Ain[((size_t)b*Dn + d)*Ln + l0 + t];
  }
  __syncthreads();
  int e = tid;
  float2 acc[TLn];
  #pragma unroll
  for (int t = 0; t < TLn; ++t) acc[t] = make_float2(0.f, 0.f);
  for (int d = 0; d < Dn; ++d){
    float2 w = W[(size_t)d*Dn + e];
    #pragma unroll
    for (int t = 0; t < TLn; ++t) acc[t] = cfma(Ash[d*TLn + t], w, acc[t]);
  }
  #pragma unroll
  for (int t = 0; t < TLn; ++t)
    Q[((size_t)b*Ln + l0 + t)*Dn + e] = acc[t];
}

// Fused score + magminmax + PV per (b,h,q) row.
__global__ void attn_fused_kernel(const float2* __restrict__ Q, const float2* __restrict__ K,
                                  const float2* __restrict__ V, float2* __restrict__ O){
  int q = blockIdx.x & (Ln-1);
  int h = (blockIdx.x >> 8) & (Hn-1);
  int b = blockIdx.x >> 11;
  int tid = threadIdx.x;
  __shared__ float2 qrow[DKn];
  __shared__ float2 srow[Ln];
  __shared__ float red[256];
  __shared__ float2 pv[256];
  if (tid < DKn) qrow[tid] = Q[((size_t)(b*Ln + q))*Dn + h*DKn + tid];
  __syncthreads();
  const float2* krow = K + ((size_t)(b*Ln + tid))*Dn + h*DKn;
  float2 s = make_float2(0.f, 0.f);
  #pragma unroll 8
  for (int d = 0; d < DKn; ++d) s = cfma(qrow[d], krow[d], s);
  const float scl = 0.17677669529663687f;   // 1/sqrt(32)
  s.x *= scl; s.y *= scl;
  float mag = sqrtf(s.x*s.x + s.y*s.y);
  red[tid] = mag; __syncthreads();
  for (int st = 128; st > 0; st >>= 1){
    if (tid < st) red[tid] = fminf(red[tid], red[tid+st]);
    __syncthreads();
  }
  float mn = red[0]; __syncthreads();
  red[tid] = mag; __syncthreads();
  for (int st = 128; st > 0; st >>= 1){
    if (tid < st) red[tid] = fmaxf(red[tid], red[tid+st]);
    __syncthreads();
  }
  float mx = red[0];
  float f = ((mag - mn) / (mx - mn + EPSf)) / (mag + EPSf);
  srow[tid] = make_float2(s.x*f, s.y*f);
  __syncthreads();
  // PV: 8 chunks of 32 k's, 32 dv lanes each
  int dv = tid & (DVn-1);
  int ch = tid >> 5;
  float2 acc = make_float2(0.f, 0.f);
  const float2* vbase = V + (size_t)b*Ln*Dn + h*DVn + dv;
  for (int k2 = ch*32; k2 < ch*32 + 32; ++k2)
    acc = cfma(srow[k2], vbase[(size_t)k2*Dn], acc);
  pv[tid] = acc; __syncthreads();
  if (tid < 128) pv[tid] = c_add(pv[tid], pv[tid+128]);
  __syncthreads();
  if (tid < 64) pv[tid] = c_add(pv[tid], pv[tid+64]);
  __syncthreads();
  if (tid < 32){
    float2 r = c_add(pv[tid], pv[tid+32]);
    O[((size_t)(b*Ln + q))*Dn + h*DVn + tid] = r;
  }
}

// Xc[b, d, seg*L + l] = sum_e O[b,l,e] * Wo[e,d]
__global__ void wo_xc_kernel(const float2* __restrict__ O, const float2* __restrict__ Wo,
                             float2* __restrict__ Xc, int seg){
  __shared__ float2 Osh[TLn*Dn];   // Osh[t*Dn + e]
  int b = blockIdx.x / (Ln/TLn);
  int l0 = (blockIdx.x % (Ln/TLn)) * TLn;
  int tid = threadIdx.x;
  for (int j = tid; j < TLn*Dn; j += 256){
    int t = j >> 8, e = j & (Dn-1);
    Osh[j] = O[((size_t)b*Ln + l0 + t)*Dn + e];
  }
  __syncthreads();
  int d = tid;
  float2 acc[TLn];
  #pragma unroll
  for (int t = 0; t < TLn; ++t) acc[t] = make_float2(0.f, 0.f);
  for (int e = 0; e < Dn; ++e){
    float2 w = Wo[(size_t)e*Dn + d];
    #pragma unroll
    for (int t = 0; t < TLn; ++t) acc[t] = cfma(Osh[t*Dn + e], w, acc[t]);
  }
  #pragma unroll
  for (int t = 0; t < TLn; ++t)
    Xc[((size_t)b*Dn + d)*L4n + seg*Ln + l0 + t] = acc[t];
}

// mean over last dim (1024), one block per row
__global__ void row_mean_kernel(const float2* __restrict__ X, float2* __restrict__ y){
  int row = blockIdx.x;
  int tid = threadIdx.x;
  float sx = 0.f, sy = 0.f;
  const float2* xr = X + (size_t)row*L4n;
  for (int i = tid; i < L4n; i += 256){ float2 v = xr[i]; sx += v.x; sy += v.y; }
  __shared__ float rx[256], ry[256];
  rx[tid] = sx; ry[tid] = sy; __syncthreads();
  for (int st = 128; st > 0; st >>= 1){
    if (tid < st){ rx[tid] += rx[tid+st]; ry[tid] += ry[tid+st]; }
    __syncthreads();
  }
  if (tid == 0) y[row] = make_float2(rx[0]*(1.f/L4n), ry[0]*(1.f/L4n));
}

// gate[b,c] = sigmoid(Re z) + i sigmoid(Im z), z = sum_i w[i]*y[b, c+i-2]
__global__ void eca_gate_kernel(const float2* __restrict__ y, const float2* __restrict__ w,
                                float2* __restrict__ g, int C){
  int idx = blockIdx.x*blockDim.x + threadIdx.x;
  if (idx >= Bn*C) return;
  int c = idx % C;
  int b = idx / C;
  float2 z = make_float2(0.f, 0.f);
  #pragma unroll
  for (int i = 0; i < KEn; ++i){
    int cc = c + i - 2;
    if (cc >= 0 && cc < C) z = cfma(w[i], y[b*C + cc], z);
  }
  g[idx] = make_float2(1.f/(1.f + expf(-z.x)), 1.f/(1.f + expf(-z.y)));
}

// X[row, x] *= gate[row], rows of 1024
__global__ void eca_apply_kernel(float2* __restrict__ X, const float2* __restrict__ g){
  int idx = blockIdx.x*256 + threadIdx.x;
  int row = idx >> 10;
  X[idx] = cmul(X[idx], g[row]);
}

// R[b,o,x] = sum_c sum_i X[b,c,x+i-1] * W[o,c,i]   over length 1024
__global__ void conv_dd_kernel(const float2* __restrict__ X, const float2* __restrict__ W,
                               float2* __restrict__ R){
  int x = (blockIdx.x & 3)*256 + threadIdx.x;
  int o = (blockIdx.x >> 2) & (Dn-1);
  int b = blockIdx.x >> 10;
  float2 acc = make_float2(0.f, 0.f);
  const float2* xb = X + (size_t)b*Dn*L4n;
  const float2* wb = W + (size_t)o*Dn*KWn;
  for (int c = 0; c < Dn; ++c){
    const float2* xr = xb + (size_t)c*L4n;
    float2 w0 = wb[c*KWn+0], w1 = wb[c*KWn+1], w2 = wb[c*KWn+2];
    if (x > 0) acc = cfma(xr[x-1], w0, acc);
    acc = cfma(xr[x], w1, acc);
    if (x < L4n-1) acc = cfma(xr[x+1], w2, acc);
  }
  R[((size_t)(b*Dn + o))*L4n + x] = acc;
}

// src [B,256,1024] -> dst [B,512,1024] at channel offset coff
__global__ void place_kernel(const float2* __restrict__ src, float2* __restrict__ dst, int coff){
  int idx = blockIdx.x*256 + threadIdx.x;
  int x = idx & (L4n-1);
  int c = (idx >> 10) & (Dn-1);
  int b = idx >> 18;
  dst[((size_t)(b*2*Dn + coff + c))*L4n + x] = src[idx];
}

} // namespace

extern "C" void kernel_launch(void* const* d_in, const int* in_sizes, int n_in,
                              void* d_out, int out_size, void* d_ws, size_t ws_size,
                              hipStream_t stream){
  const float2* X1 = (const float2*)d_in[0];
  const float2* X2 = (const float2*)d_in[1];
  const float2* head_w = (const float2*)d_in[2];
  const float2* head_b = (const float2*)d_in[3];
  const float2* wq = (const float2*)d_in[4];
  const float2* wk = (const float2*)d_in[5];
  const float2* wv = (const float2*)d_in[6];
  const float2* wo = (const float2*)d_in[7];
  const float2* se = (const float2*)d_in[8];
  const float2* sc = (const float2*)d_in[9];
  const float2* te = (const float2*)d_in[10];

  float2* p = (float2*)d_ws;
  const size_t SZ_BDL = (size_t)Bn*Dn*Ln;      // 524288 complex
  const size_t SZ_X   = (size_t)Bn*Dn*L4n;     // 2097152 complex
  float2* A  = p;  p += SZ_BDL;
  float2* Bc = p;  p += SZ_BDL;
  float2* iA = p;  p += SZ_BDL;
  float2* iB = p;  p += SZ_BDL;
  float2* Qb = p;  p += SZ_BDL;
  float2* Kb = p;  p += SZ_BDL;
  float2* Vb = p;  p += SZ_BDL;
  float2* Ob = p;  p += SZ_BDL;
  float2* Xc = p;  p += SZ_X;
  float2* Rb = p;  p += SZ_X;
  float2* kb = p;  p += SZ_X;
  float2* ybuf = p; p += (size_t)Bn*2*Dn;
  float2* gbuf = p; p += (size_t)Bn*2*Dn;

  // head convs: A = conv(X1, hw0)+hb0 ; Bc = conv(X2, hw1)+hb1
  head_conv_kernel<<<(Bn*Dn*Ln)/256, 256, 0, stream>>>(X1, head_w, head_b, A);
  head_conv_kernel<<<(Bn*Dn*Ln)/256, 256, 0, stream>>>(
      X2, head_w + (size_t)Dn*CINn*KWn, head_b + Dn, Bc);

  // iA = ifft(A), iB = ifft(Bc)  (length 256 rows)
  fft_rows_kernel<256,8><<<Bn*Dn, 256, 0, stream>>>(A,  iA, 1.0f, 1.0f/256.0f);
  fft_rows_kernel<256,8><<<Bn*Dn, 256, 0, stream>>>(Bc, iB, 1.0f, 1.0f/256.0f);

  auto run_ssca = [&](const float2* Ap, const float2* Bp, int set, float2* Rout){
    for (int m = 0; m < 4; ++m){
      // m: 0=(A,A,A) 1=(B,B,B) 2=(A,B,B) 3=(B,A,A)
      const float2* qin  = (m == 0 || m == 2) ? Ap : Bp;
      const float2* kvin = (m == 0 || m == 3) ? Ap : Bp;
      const float2* Wq_ = wq + (size_t)(set*4 + m)*Dn*Dn;
      const float2* Wk_ = wk + (size_t)(set*4 + m)*Dn*Dn;
      const float2* Wv_ = wv + (size_t)(set*4 + m)*Dn*Dn;
      const float2* Wo_ = wo + (size_t)(set*4 + m)*Dn*Dn;
      proj_kernel<<<Bn*(Ln/TLn), 256, 0, stream>>>(qin,  Wq_, Qb);
      proj_kernel<<<Bn*(Ln/TLn), 256, 0, stream>>>(kvin, Wk_, Kb);
      proj_kernel<<<Bn*(Ln/TLn), 256, 0, stream>>>(kvin, Wv_, Vb);
      attn_fused_kernel<<<Bn*Hn*Ln, 256, 0, stream>>>(Qb, Kb, Vb, Ob);
      wo_xc_kernel<<<Bn*(Ln/TLn), 256, 0, stream>>>(Ob, Wo_, Xc, m);
    }
    // eca on Xc [B, 256, 1024]
    row_mean_kernel<<<Bn*Dn, 256, 0, stream>>>(Xc, ybuf);
    eca_gate_kernel<<<(Bn*Dn + 255)/256, 256, 0, stream>>>(ybuf, se + set*KEn, gbuf, Dn);
    eca_apply_kernel<<<(int)(SZ_X/256), 256, 0, stream>>>(Xc, gbuf);
    // conv1d (D x D x 3) over length 1024
    conv_dd_kernel<<<Bn*Dn*(L4n/256), 256, 0, stream>>>(
        Xc, sc + (size_t)set*Dn*Dn*KWn, Rout);
  };

  run_ssca(A,  Bc, 0, Rb);   // R
  run_ssca(iA, iB, 1, kb);   // kk

  float2* out0 = (float2*)d_out;                   // eca(R2, te0): [B, 512, 1024]
  float2* out1 = out0 + (size_t)Bn*2*Dn*L4n;       // eca(k2, te1)

  // R2 = concat(R, fft(kk)); k2 = concat(kk, ifft(R))
  place_kernel<<<(int)(SZ_X/256), 256, 0, stream>>>(Rb, out0, 0);
  fft_rows_kernel<1024,10><<<Bn*Dn, 256, 0, stream>>>(kb, Xc, -1.0f, 1.0f);
  place_kernel<<<(int)(SZ_X/256), 256, 0, stream>>>(Xc, out0, Dn);
  place_kernel<<<(int)(SZ_X/256), 256, 0, stream>>>(kb, out1, 0);
  fft_rows_kernel<1024,10><<<Bn*Dn, 256, 0, stream>>>(Rb, Xc, 1.0f, 1.0f/1024.0f);
  place_kernel<<<(int)(SZ_X/256), 256, 0, stream>>>(Xc, out1, Dn);

  // top eca on both outputs, in place
  for (int t = 0; t < 2; ++t){
    float2* op = (t == 0) ? out0 : out1;
    row_mean_kernel<<<Bn*2*Dn, 256, 0, stream>>>(op, ybuf);
    eca_gate_kernel<<<(Bn*2*Dn + 255)/256, 256, 0, stream>>>(ybuf, te + t*KEn, gbuf, 2*Dn);
    eca_apply_kernel<<<(Bn*2*Dn*L4n)/256, 256, 0, stream>>>(op, gbuf);
  }
}

// Round 2
// 3079.589 us; speedup vs baseline: 1.4840x; 1.4840x over previous
//
#include <hip/hip_runtime.h>
#include <math.h>

namespace {

constexpr int Bn = 8, CINn = 16, Ln = 256, Dn = 256, Hn = 8, DKn = 32, DVn = 32;
constexpr int KWn = 3, KEn = 5, L4n = 1024;
constexpr float EPSf = 1e-9f;

__device__ __forceinline__ float2 cmul(float2 a, float2 b){
  return make_float2(a.x*b.x - a.y*b.y, a.x*b.y + a.y*b.x);
}
__device__ __forceinline__ float2 cfma(float2 a, float2 b, float2 c){
  c.x = fmaf(a.x, b.x, c.x); c.x = fmaf(-a.y, b.y, c.x);
  c.y = fmaf(a.x, b.y, c.y); c.y = fmaf(a.y, b.x, c.y);
  return c;
}
__device__ __forceinline__ float2 c_add(float2 a, float2 b){
  return make_float2(a.x + b.x, a.y + b.y);
}

// A[b,o,l] = sum_c sum_i X[b,c,l+i-1] * hw[o,c,i] + hb[o]
__global__ void head_conv_kernel(const float2* __restrict__ X, const float2* __restrict__ hw,
                                 const float2* __restrict__ hb, float2* __restrict__ out){
  int idx = blockIdx.x * blockDim.x + threadIdx.x;
  if (idx >= Bn*Dn*Ln) return;
  int l = idx & (Ln-1);
  int o = (idx >> 8) & (Dn-1);
  int b = idx >> 16;
  float2 acc = hb[o];
  for (int c = 0; c < CINn; ++c){
    const float2* xr = X + (size_t)(b*CINn + c)*Ln;
    const float2* wr = hw + (size_t)(o*CINn + c)*KWn;
    #pragma unroll
    for (int i = 0; i < KWn; ++i){
      int ll = l + i - 1;
      if (ll >= 0 && ll < Ln) acc = cfma(xr[ll], wr[i], acc);
    }
  }
  out[idx] = acc;
}

// In-LDS radix-2 FFT, one block (256 threads) per row of N complex.
template<int N, int LOG>
__global__ void fft_rows_kernel(const float2* __restrict__ in, float2* __restrict__ out,
                                float sign, float scale){
  __shared__ float2 buf[N];
  int row = blockIdx.x;
  const float2* src = in + (size_t)row * N;
  int tid = threadIdx.x;
  for (int i = tid; i < N; i += 256){
    unsigned r = __brev((unsigned)i) >> (32 - LOG);
    buf[r] = src[i];
  }
  __syncthreads();
  for (int len = 2; len <= N; len <<= 1){
    int half = len >> 1;
    for (int bf = tid; bf < N/2; bf += 256){
      int blk = bf / half;
      int pos = bf - blk*half;
      int i0 = blk*len + pos;
      int i1 = i0 + half;
      float ang = sign * 6.2831853071795864f * (float)pos / (float)len;
      float s, c;
      sincosf(ang, &s, &c);
      float2 w = make_float2(c, s);
      float2 u = buf[i0];
      float2 t = cmul(w, buf[i1]);
      buf[i0] = make_float2(u.x + t.x, u.y + t.y);
      buf[i1] = make_float2(u.x - t.x, u.y - t.y);
    }
    __syncthreads();
  }
  float2* dst = out + (size_t)row * N;
  for (int i = tid; i < N; i += 256)
    dst[i] = make_float2(buf[i].x * scale, buf[i].y * scale);
}

// ---------------- fused QKV projection, register-tiled ----------------
// Q[b,l,e] = sum_d Ain[b,d,l] * W[d,e]; tile 64 l x 64 e, K-chunk 16.
// thread: tx (e, strided by 16), ty (l, consecutive 4).
__global__ void qkv_proj_kernel(const float2* __restrict__ qin, const float2* __restrict__ kvin,
                                const float2* __restrict__ Wq_, const float2* __restrict__ Wk_,
                                const float2* __restrict__ Wv_,
                                float2* __restrict__ Qb, float2* __restrict__ Kb,
                                float2* __restrict__ Vb){
  int which = blockIdx.y;
  const float2* Ain = (which == 0) ? qin : kvin;
  const float2* W   = (which == 0) ? Wq_ : (which == 1 ? Wk_ : Wv_);
  float2* Out       = (which == 0) ? Qb  : (which == 1 ? Kb  : Vb);
  int bx = blockIdx.x;
  int et = bx & 3, lt = (bx >> 2) & 3, b = bx >> 4;
  int l0 = lt*64, e0 = et*64;
  __shared__ float2 As[16][64];   // As[dd][ll]
  __shared__ float2 Ws[16][64];   // Ws[dd][ee]
  int tid = threadIdx.x;
  int tx = tid & 15, ty = tid >> 4;
  float2 acc[4][4];               // [l(k)][e(j)]
  #pragma unroll
  for (int k = 0; k < 4; ++k)
    #pragma unroll
    for (int j = 0; j < 4; ++j) acc[k][j] = make_float2(0.f, 0.f);
  for (int d0 = 0; d0 < Dn; d0 += 16){
    for (int j = tid; j < 16*64; j += 256){
      int dd = j >> 6, ll = j & 63;
      As[dd][ll] = Ain[((size_t)b*Dn + d0 + dd)*Ln + l0 + ll];
    }
    for (int j = tid; j < 16*64; j += 256){
      int dd = j >> 6, ee = j & 63;
      Ws[dd][ee] = W[(size_t)(d0 + dd)*Dn + e0 + ee];
    }
    __syncthreads();
    #pragma unroll
    for (int dd = 0; dd < 16; ++dd){
      float2 a[4], w[4];
      #pragma unroll
      for (int k = 0; k < 4; ++k) a[k] = As[dd][ty*4 + k];
      #pragma unroll
      for (int j = 0; j < 4; ++j) w[j] = Ws[dd][tx + j*16];
      #pragma unroll
      for (int k = 0; k < 4; ++k)
        #pragma unroll
        for (int j = 0; j < 4; ++j) acc[k][j] = cfma(a[k], w[j], acc[k][j]);
    }
    __syncthreads();
  }
  #pragma unroll
  for (int k = 0; k < 4; ++k)
    #pragma unroll
    for (int j = 0; j < 4; ++j)
      Out[((size_t)(b*Ln + l0 + ty*4 + k))*Dn + e0 + tx + j*16] = acc[k][j];
}

// Fused score + magminmax + PV per (b,h,q) row.
__global__ void attn_fused_kernel(const float2* __restrict__ Q, const float2* __restrict__ K,
                                  const float2* __restrict__ V, float2* __restrict__ O){
  int q = blockIdx.x & (Ln-1);
  int h = (blockIdx.x >> 8) & (Hn-1);
  int b = blockIdx.x >> 11;
  int tid = threadIdx.x;
  __shared__ float2 qrow[DKn];
  __shared__ float2 srow[Ln];
  __shared__ float red[256];
  __shared__ float2 pv[256];
  if (tid < DKn) qrow[tid] = Q[((size_t)(b*Ln + q))*Dn + h*DKn + tid];
  __syncthreads();
  const float2* krow = K + ((size_t)(b*Ln + tid))*Dn + h*DKn;
  float2 s = make_float2(0.f, 0.f);
  #pragma unroll 8
  for (int d = 0; d < DKn; ++d) s = cfma(qrow[d], krow[d], s);
  const float scl = 0.17677669529663687f;
  s.x *= scl; s.y *= scl;
  float mag = sqrtf(s.x*s.x + s.y*s.y);
  red[tid] = mag; __syncthreads();
  for (int st = 128; st > 0; st >>= 1){
    if (tid < st) red[tid] = fminf(red[tid], red[tid+st]);
    __syncthreads();
  }
  float mn = red[0]; __syncthreads();
  red[tid] = mag; __syncthreads();
  for (int st = 128; st > 0; st >>= 1){
    if (tid < st) red[tid] = fmaxf(red[tid], red[tid+st]);
    __syncthreads();
  }
  float mx = red[0];
  float f = ((mag - mn) / (mx - mn + EPSf)) / (mag + EPSf);
  srow[tid] = make_float2(s.x*f, s.y*f);
  __syncthreads();
  int dv = tid & (DVn-1);
  int ch = tid >> 5;
  float2 acc = make_float2(0.f, 0.f);
  const float2* vbase = V + (size_t)b*Ln*Dn + h*DVn + dv;
  for (int k2 = ch*32; k2 < ch*32 + 32; ++k2)
    acc = cfma(srow[k2], vbase[(size_t)k2*Dn], acc);
  pv[tid] = acc; __syncthreads();
  if (tid < 128) pv[tid] = c_add(pv[tid], pv[tid+128]);
  __syncthreads();
  if (tid < 64) pv[tid] = c_add(pv[tid], pv[tid+64]);
  __syncthreads();
  if (tid < 32){
    float2 r = c_add(pv[tid], pv[tid+32]);
    O[((size_t)(b*Ln + q))*Dn + h*DVn + tid] = r;
  }
}

// ---------------- Wo projection into Xc, register-tiled ----------------
// Xc[b,d,seg*L+l] = sum_e O[b,l,e] * Wo[e,d]; tile 64 d x 64 l, K-chunk 16.
// thread: tx (l, strided 16), ty (d, consecutive 4).
__global__ void wo_xc_tiled(const float2* __restrict__ O, const float2* __restrict__ Wo_,
                            float2* __restrict__ Xc, int seg){
  int bx = blockIdx.x;
  int dt = bx & 3, lt = (bx >> 2) & 3, b = bx >> 4;
  int l0 = lt*64, d0 = dt*64;
  __shared__ float2 Os[16][65];   // Os[ee][ll], padded
  __shared__ float2 Ws[16][64];   // Ws[ee][dd]
  int tid = threadIdx.x;
  int tx = tid & 15, ty = tid >> 4;
  float2 acc[4][4];               // [d(k)][l(j)]
  #pragma unroll
  for (int k = 0; k < 4; ++k)
    #pragma unroll
    for (int j = 0; j < 4; ++j) acc[k][j] = make_float2(0.f, 0.f);
  for (int e0 = 0; e0 < Dn; e0 += 16){
    for (int j = tid; j < 16*64; j += 256){
      int ll = j >> 4, ee = j & 15;
      Os[ee][ll] = O[((size_t)(b*Ln + l0 + ll))*Dn + e0 + ee];
    }
    for (int j = tid; j < 16*64; j += 256){
      int ee = j >> 6, dd = j & 63;
      Ws[ee][dd] = Wo_[(size_t)(e0 + ee)*Dn + d0 + dd];
    }
    __syncthreads();
    #pragma unroll
    for (int ee = 0; ee < 16; ++ee){
      float2 a[4], w[4];
      #pragma unroll
      for (int j = 0; j < 4; ++j) a[j] = Os[ee][tx + j*16];
      #pragma unroll
      for (int k = 0; k < 4; ++k) w[k] = Ws[ee][ty*4 + k];
      #pragma unroll
      for (int k = 0; k < 4; ++k)
        #pragma unroll
        for (int j = 0; j < 4; ++j) acc[k][j] = cfma(a[j], w[k], acc[k][j]);
    }
    __syncthreads();
  }
  #pragma unroll
  for (int k = 0; k < 4; ++k)
    #pragma unroll
    for (int j = 0; j < 4; ++j)
      Xc[((size_t)(b*Dn + d0 + ty*4 + k))*L4n + seg*Ln + l0 + tx + j*16] = acc[k][j];
}

// mean over last dim (1024), one block per row
__global__ void row_mean_kernel(const float2* __restrict__ X, float2* __restrict__ y){
  int row = blockIdx.x;
  int tid = threadIdx.x;
  float sx = 0.f, sy = 0.f;
  const float2* xr = X + (size_t)row*L4n;
  for (int i = tid; i < L4n; i += 256){ float2 v = xr[i]; sx += v.x; sy += v.y; }
  __shared__ float rx[256], ry[256];
  rx[tid] = sx; ry[tid] = sy; __syncthreads();
  for (int st = 128; st > 0; st >>= 1){
    if (tid < st){ rx[tid] += rx[tid+st]; ry[tid] += ry[tid+st]; }
    __syncthreads();
  }
  if (tid == 0) y[row] = make_float2(rx[0]*(1.f/L4n), ry[0]*(1.f/L4n));
}

__global__ void eca_gate_kernel(const float2* __restrict__ y, const float2* __restrict__ w,
                                float2* __restrict__ g, int C){
  int idx = blockIdx.x*blockDim.x + threadIdx.x;
  if (idx >= Bn*C) return;
  int c = idx % C;
  int b = idx / C;
  float2 z = make_float2(0.f, 0.f);
  #pragma unroll
  for (int i = 0; i < KEn; ++i){
    int cc = c + i - 2;
    if (cc >= 0 && cc < C) z = cfma(w[i], y[b*C + cc], z);
  }
  g[idx] = make_float2(1.f/(1.f + expf(-z.x)), 1.f/(1.f + expf(-z.y)));
}

__global__ void eca_apply_kernel(float2* __restrict__ X, const float2* __restrict__ g){
  int idx = blockIdx.x*256 + threadIdx.x;
  int row = idx >> 10;
  X[idx] = cmul(X[idx], g[row]);
}

// ---------------- D x D x 3 conv over length 1024, register-tiled ----------------
// R[b,o,x] = sum_c sum_i X[b,c,x+i-1] * W[o,c,i]
// tile: 64 o x 64 x per block, K-chunk 16 channels; thread: tx (x, strided 16),
// ty (o, consecutive 4); 4x4 outputs per thread.
__global__ void conv_dd_tiled(const float2* __restrict__ X, const float2* __restrict__ W,
                              float2* __restrict__ R){
  __shared__ float2 Xs[16][66];   // Xs[cc][xx], xx -> global x0+xx-1
  __shared__ float2 Ws[64][49];   // Ws[o][cc*3+i], padded row (49) -> conflict-free
  int bx = blockIdx.x;
  int xt = bx & 15, ot = (bx >> 4) & 3, b = bx >> 6;
  int x0 = xt*64, o0 = ot*64;
  int tid = threadIdx.x;
  int tx = tid & 15, ty = tid >> 4;
  float2 acc[4][4];               // [o(k)][x(j)]
  #pragma unroll
  for (int k = 0; k < 4; ++k)
    #pragma unroll
    for (int j = 0; j < 4; ++j) acc[k][j] = make_float2(0.f, 0.f);
  const float2* xb = X + (size_t)b*Dn*L4n;
  for (int c0 = 0; c0 < Dn; c0 += 16){
    for (int j = tid; j < 16*66; j += 256){
      int cc = j / 66, xx = j % 66;
      int gx = x0 + xx - 1;
      float2 v = make_float2(0.f, 0.f);
      if (gx >= 0 && gx < L4n) v = xb[(size_t)(c0 + cc)*L4n + gx];
      Xs[cc][xx] = v;
    }
    for (int j = tid; j < 64*48; j += 256){
      int o = j / 48, r = j % 48;   // r = cc*3 + i
      Ws[o][r] = W[(size_t)(o0 + o)*Dn*KWn + c0*KWn + r];
    }
    __syncthreads();
    #pragma unroll
    for (int cc = 0; cc < 16; ++cc){
      float2 xv[4][3];
      #pragma unroll
      for (int j = 0; j < 4; ++j)
        #pragma unroll
        for (int i = 0; i < 3; ++i) xv[j][i] = Xs[cc][tx + j*16 + i];
      #pragma unroll
      for (int k = 0; k < 4; ++k){
        float2 w0 = Ws[ty*4 + k][cc*3 + 0];
        float2 w1 = Ws[ty*4 + k][cc*3 + 1];
        float2 w2 = Ws[ty*4 + k][cc*3 + 2];
        #pragma unroll
        for (int j = 0; j < 4; ++j){
          acc[k][j] = cfma(xv[j][0], w0, acc[k][j]);
          acc[k][j] = cfma(xv[j][1], w1, acc[k][j]);
          acc[k][j] = cfma(xv[j][2], w2, acc[k][j]);
        }
      }
    }
    __syncthreads();
  }
  #pragma unroll
  for (int k = 0; k < 4; ++k)
    #pragma unroll
    for (int j = 0; j < 4; ++j)
      R[((size_t)(b*Dn + o0 + ty*4 + k))*L4n + x0 + tx + j*16] = acc[k][j];
}

// src [B,256,1024] -> dst [B,512,1024] at channel offset coff
__global__ void place_kernel(const float2* __restrict__ src, float2* __restrict__ dst, int coff){
  int idx = blockIdx.x*256 + threadIdx.x;
  int x = idx & (L4n-1);
  int c = (idx >> 10) & (Dn-1);
  int b = idx >> 18;
  dst[((size_t)(b*2*Dn + coff + c))*L4n + x] = src[idx];
}

} // namespace

extern "C" void kernel_launch(void* const* d_in, const int* in_sizes, int n_in,
                              void* d_out, int out_size, void* d_ws, size_t ws_size,
                              hipStream_t stream){
  const float2* X1 = (const float2*)d_in[0];
  const float2* X2 = (const float2*)d_in[1];
  const float2* head_w = (const float2*)d_in[2];
  const float2* head_b = (const float2*)d_in[3];
  const float2* wq = (const float2*)d_in[4];
  const float2* wk = (const float2*)d_in[5];
  const float2* wv = (const float2*)d_in[6];
  const float2* wo = (const float2*)d_in[7];
  const float2* se = (const float2*)d_in[8];
  const float2* sc = (const float2*)d_in[9];
  const float2* te = (const float2*)d_in[10];

  float2* p = (float2*)d_ws;
  const size_t SZ_BDL = (size_t)Bn*Dn*Ln;
  const size_t SZ_X   = (size_t)Bn*Dn*L4n;
  float2* A  = p;  p += SZ_BDL;
  float2* Bc = p;  p += SZ_BDL;
  float2* iA = p;  p += SZ_BDL;
  float2* iB = p;  p += SZ_BDL;
  float2* Qb = p;  p += SZ_BDL;
  float2* Kb = p;  p += SZ_BDL;
  float2* Vb = p;  p += SZ_BDL;
  float2* Ob = p;  p += SZ_BDL;
  float2* Xc = p;  p += SZ_X;
  float2* Rb = p;  p += SZ_X;
  float2* kb = p;  p += SZ_X;
  float2* ybuf = p; p += (size_t)Bn*2*Dn;
  float2* gbuf = p; p += (size_t)Bn*2*Dn;

  head_conv_kernel<<<(Bn*Dn*Ln)/256, 256, 0, stream>>>(X1, head_w, head_b, A);
  head_conv_kernel<<<(Bn*Dn*Ln)/256, 256, 0, stream>>>(
      X2, head_w + (size_t)Dn*CINn*KWn, head_b + Dn, Bc);

  fft_rows_kernel<256,8><<<Bn*Dn, 256, 0, stream>>>(A,  iA, 1.0f, 1.0f/256.0f);
  fft_rows_kernel<256,8><<<Bn*Dn, 256, 0, stream>>>(Bc, iB, 1.0f, 1.0f/256.0f);

  auto run_ssca = [&](const float2* Ap, const float2* Bp, int set, float2* Rout){
    for (int m = 0; m < 4; ++m){
      const float2* qin  = (m == 0 || m == 2) ? Ap : Bp;
      const float2* kvin = (m == 0 || m == 3) ? Ap : Bp;
      const float2* Wq_ = wq + (size_t)(set*4 + m)*Dn*Dn;
      const float2* Wk_ = wk + (size_t)(set*4 + m)*Dn*Dn;
      const float2* Wv_ = wv + (size_t)(set*4 + m)*Dn*Dn;
      const float2* Wo_ = wo + (size_t)(set*4 + m)*Dn*Dn;
      qkv_proj_kernel<<<dim3(Bn*16, 3), 256, 0, stream>>>(qin, kvin, Wq_, Wk_, Wv_, Qb, Kb, Vb);
      attn_fused_kernel<<<Bn*Hn*Ln, 256, 0, stream>>>(Qb, Kb, Vb, Ob);
      wo_xc_tiled<<<Bn*16, 256, 0, stream>>>(Ob, Wo_, Xc, m);
    }
    row_mean_kernel<<<Bn*Dn, 256, 0, stream>>>(Xc, ybuf);
    eca_gate_kernel<<<(Bn*Dn + 255)/256, 256, 0, stream>>>(ybuf, se + set*KEn, gbuf, Dn);
    eca_apply_kernel<<<(int)(SZ_X/256), 256, 0, stream>>>(Xc, gbuf);
    conv_dd_tiled<<<Bn*4*16, 256, 0, stream>>>(Xc, sc + (size_t)set*Dn*Dn*KWn, Rout);
  };

  run_ssca(A,  Bc, 0, Rb);
  run_ssca(iA, iB, 1, kb);

  float2* out0 = (float2*)d_out;
  float2* out1 = out0 + (size_t)Bn*2*Dn*L4n;

  place_kernel<<<(int)(SZ_X/256), 256, 0, stream>>>(Rb, out0, 0);
  fft_rows_kernel<1024,10><<<Bn*Dn, 256, 0, stream>>>(kb, Xc, -1.0f, 1.0f);
  place_kernel<<<(int)(SZ_X/256), 256, 0, stream>>>(Xc, out0, Dn);
  place_kernel<<<(int)(SZ_X/256), 256, 0, stream>>>(kb, out1, 0);
  fft_rows_kernel<1024,10><<<Bn*Dn, 256, 0, stream>>>(Rb, Xc, 1.0f, 1.0f/1024.0f);
  place_kernel<<<(int)(SZ_X/256), 256, 0, stream>>>(Xc, out1, Dn);

  for (int t = 0; t < 2; ++t){
    float2* op = (t == 0) ? out0 : out1;
    row_mean_kernel<<<Bn*2*Dn, 256, 0, stream>>>(op, ybuf);
    eca_gate_kernel<<<(Bn*2*Dn + 255)/256, 256, 0, stream>>>(ybuf, te + t*KEn, gbuf, 2*Dn);
    eca_apply_kernel<<<(Bn*2*Dn*L4n)/256, 256, 0, stream>>>(op, gbuf);
  }
}

// Round 3
// 2325.955 us; speedup vs baseline: 1.9648x; 1.3240x over previous
//
#include <hip/hip_runtime.h>
#include <math.h>

namespace {

constexpr int Bn = 8, CINn = 16, Ln = 256, Dn = 256, Hn = 8, DKn = 32, DVn = 32;
constexpr int KWn = 3, KEn = 5, L4n = 1024;
constexpr float EPSf = 1e-9f;

__device__ __forceinline__ float2 cmul(float2 a, float2 b){
  return make_float2(a.x*b.x - a.y*b.y, a.x*b.y + a.y*b.x);
}
__device__ __forceinline__ float2 cfma(float2 a, float2 b, float2 c){
  c.x = fmaf(a.x, b.x, c.x); c.x = fmaf(-a.y, b.y, c.x);
  c.y = fmaf(a.x, b.y, c.y); c.y = fmaf(a.y, b.x, c.y);
  return c;
}
__device__ __forceinline__ float2 c_add(float2 a, float2 b){
  return make_float2(a.x + b.x, a.y + b.y);
}

// A[b,o,l] = sum_c sum_i X[b,c,l+i-1] * hw[o,c,i] + hb[o]
__global__ void head_conv_kernel(const float2* __restrict__ X, const float2* __restrict__ hw,
                                 const float2* __restrict__ hb, float2* __restrict__ out){
  int idx = blockIdx.x * blockDim.x + threadIdx.x;
  if (idx >= Bn*Dn*Ln) return;
  int l = idx & (Ln-1);
  int o = (idx >> 8) & (Dn-1);
  int b = idx >> 16;
  float2 acc = hb[o];
  for (int c = 0; c < CINn; ++c){
    const float2* xr = X + (size_t)(b*CINn + c)*Ln;
    const float2* wr = hw + (size_t)(o*CINn + c)*KWn;
    #pragma unroll
    for (int i = 0; i < KWn; ++i){
      int ll = l + i - 1;
      if (ll >= 0 && ll < Ln) acc = cfma(xr[ll], wr[i], acc);
    }
  }
  out[idx] = acc;
}

// In-LDS radix-2 FFT with twiddle table; rows mapped through (chans, coff) so
// src/dst can live inside the [B, chans, N] output tensors.
// row = b*256 + c ; linear offset = (b*chans + coff + c) * N.
template<int N, int LOG>
__global__ void fft_rows_kernel(const float2* __restrict__ src0, float2* __restrict__ dst0,
                                int schans, int scoff, int dchans, int dcoff,
                                float sign, float scale){
  __shared__ float2 buf[N];
  __shared__ float2 tw[N/2];
  int row = blockIdx.x;
  int rb = row >> 8, rc = row & 255;
  const float2* src = src0 + (size_t)(rb*schans + scoff + rc)*N;
  float2* dst = dst0 + (size_t)(rb*dchans + dcoff + rc)*N;
  int tid = threadIdx.x;
  for (int i = tid; i < N/2; i += 256){
    float a = sign * 6.2831853071795864f * (float)i / (float)N;
    float s, c; __sincosf(a, &s, &c);
    tw[i] = make_float2(c, s);
  }
  for (int i = tid; i < N; i += 256){
    unsigned r = __brev((unsigned)i) >> (32 - LOG);
    buf[r] = src[i];
  }
  __syncthreads();
  for (int st = 1; st <= LOG; ++st){
    int half = 1 << (st-1);
    for (int bf = tid; bf < N/2; bf += 256){
      int blk = bf >> (st-1);
      int pos = bf & (half-1);
      int i0 = (blk << st) + pos;
      int i1 = i0 + half;
      float2 w = tw[pos << (LOG-st)];
      float2 u = buf[i0];
      float2 t = cmul(w, buf[i1]);
      buf[i0] = make_float2(u.x + t.x, u.y + t.y);
      buf[i1] = make_float2(u.x - t.x, u.y - t.y);
    }
    __syncthreads();
  }
  for (int i = tid; i < N; i += 256)
    dst[i] = make_float2(buf[i].x * scale, buf[i].y * scale);
}

// ---------------- fused QKV projection for mcount m's in one launch ----------
// blockIdx.y = ml*3 + which ; m = m0 + ml.
// Q[b,l,e] = sum_d Ain[b,d,l] * W[d,e]; tile 64 l x 64 e, K-chunk 16.
__global__ void qkv_proj_kernel(const float2* __restrict__ Ap, const float2* __restrict__ Bp,
                                const float2* __restrict__ wqs, const float2* __restrict__ wks,
                                const float2* __restrict__ wvs,
                                float2* __restrict__ Qb, float2* __restrict__ Kb,
                                float2* __restrict__ Vb, int m0, size_t mstride){
  int my = blockIdx.y;
  int ml = my / 3, which = my - ml*3;
  int m = m0 + ml;
  const float2* Ain;
  if (which == 0) Ain = (m == 0 || m == 2) ? Ap : Bp;   // qin
  else            Ain = (m == 0 || m == 3) ? Ap : Bp;   // kvin
  const float2* W = ((which == 0) ? wqs : (which == 1) ? wks : wvs) + (size_t)m*Dn*Dn;
  float2* Out = ((which == 0) ? Qb : (which == 1) ? Kb : Vb) + (size_t)ml*mstride;
  int bx = blockIdx.x;
  int et = bx & 3, lt = (bx >> 2) & 3, b = bx >> 4;
  int l0 = lt*64, e0 = et*64;
  __shared__ float2 As[16][64];
  __shared__ float2 Ws[16][64];
  int tid = threadIdx.x;
  int tx = tid & 15, ty = tid >> 4;
  float2 acc[4][4];
  #pragma unroll
  for (int k = 0; k < 4; ++k)
    #pragma unroll
    for (int j = 0; j < 4; ++j) acc[k][j] = make_float2(0.f, 0.f);
  for (int d0 = 0; d0 < Dn; d0 += 16){
    for (int j = tid; j < 16*64; j += 256){
      int dd = j >> 6, ll = j & 63;
      As[dd][ll] = Ain[((size_t)b*Dn + d0 + dd)*Ln + l0 + ll];
    }
    for (int j = tid; j < 16*64; j += 256){
      int dd = j >> 6, ee = j & 63;
      Ws[dd][ee] = W[(size_t)(d0 + dd)*Dn + e0 + ee];
    }
    __syncthreads();
    #pragma unroll
    for (int dd = 0; dd < 16; ++dd){
      float2 a[4], w[4];
      #pragma unroll
      for (int k = 0; k < 4; ++k) a[k] = As[dd][ty*4 + k];
      #pragma unroll
      for (int j = 0; j < 4; ++j) w[j] = Ws[dd][tx + j*16];
      #pragma unroll
      for (int k = 0; k < 4; ++k)
        #pragma unroll
        for (int j = 0; j < 4; ++j) acc[k][j] = cfma(a[k], w[j], acc[k][j]);
    }
    __syncthreads();
  }
  #pragma unroll
  for (int k = 0; k < 4; ++k)
    #pragma unroll
    for (int j = 0; j < 4; ++j)
      Out[((size_t)(b*Ln + l0 + ty*4 + k))*Dn + e0 + tx + j*16] = acc[k][j];
}

// Fused score + magminmax + PV per (b,h,q); blockIdx.y = ml.
__global__ void attn_fused_kernel(const float2* __restrict__ Qb, const float2* __restrict__ Kb,
                                  const float2* __restrict__ Vb, float2* __restrict__ Ob,
                                  size_t mstride){
  const float2* Q = Qb + (size_t)blockIdx.y*mstride;
  const float2* K = Kb + (size_t)blockIdx.y*mstride;
  const float2* V = Vb + (size_t)blockIdx.y*mstride;
  float2* O = Ob + (size_t)blockIdx.y*mstride;
  int q = blockIdx.x & (Ln-1);
  int h = (blockIdx.x >> 8) & (Hn-1);
  int b = blockIdx.x >> 11;
  int tid = threadIdx.x;
  int lane = tid & 63, wv = tid >> 6;
  __shared__ float2 qrow[DKn];
  __shared__ float2 srow[Ln];
  __shared__ float wred[8];
  __shared__ float2 pvs[4][32];
  if (tid < DKn) qrow[tid] = Q[((size_t)(b*Ln + q))*Dn + h*DKn + tid];
  __syncthreads();
  const float4* kr4 = (const float4*)(K + ((size_t)(b*Ln + tid))*Dn + h*DKn);
  float2 s = make_float2(0.f, 0.f);
  #pragma unroll
  for (int d4 = 0; d4 < DKn/2; ++d4){
    float4 kk = kr4[d4];
    s = cfma(qrow[2*d4],   make_float2(kk.x, kk.y), s);
    s = cfma(qrow[2*d4+1], make_float2(kk.z, kk.w), s);
  }
  const float scl = 0.17677669529663687f;   // 1/sqrt(32)
  s.x *= scl; s.y *= scl;
  float mag = sqrtf(s.x*s.x + s.y*s.y);
  float mn = mag, mx = mag;
  #pragma unroll
  for (int off = 32; off > 0; off >>= 1){
    mn = fminf(mn, __shfl_xor(mn, off));
    mx = fmaxf(mx, __shfl_xor(mx, off));
  }
  if (lane == 0){ wred[wv] = mn; wred[4 + wv] = mx; }
  __syncthreads();
  mn = fminf(fminf(wred[0], wred[1]), fminf(wred[2], wred[3]));
  mx = fmaxf(fmaxf(wred[4], wred[5]), fmaxf(wred[6], wred[7]));
  float f = ((mag - mn) / (mx - mn + EPSf)) / (mag + EPSf);
  srow[tid] = make_float2(s.x*f, s.y*f);
  __syncthreads();
  int dv = tid & (DVn-1);
  int ch = tid >> 5;
  float2 acc = make_float2(0.f, 0.f);
  const float2* vbase = V + (size_t)b*Ln*Dn + h*DVn + dv;
  for (int k2 = ch*32; k2 < ch*32 + 32; ++k2)
    acc = cfma(srow[k2], vbase[(size_t)k2*Dn], acc);
  acc.x += __shfl_xor(acc.x, 32);
  acc.y += __shfl_xor(acc.y, 32);
  if (lane < 32) pvs[wv][lane] = acc;
  __syncthreads();
  if (tid < 32){
    float2 r = c_add(c_add(pvs[0][tid], pvs[1][tid]), c_add(pvs[2][tid], pvs[3][tid]));
    O[((size_t)(b*Ln + q))*Dn + h*DVn + tid] = r;
  }
}

// ---------------- Wo projection into Xc ----------------
// Xc[b,d,seg*L+l] = sum_e O[b,l,e] * Wo[e,d]; tile 32 d x 64 l; blockIdx.y = ml.
__global__ void wo_xc_tiled(const float2* __restrict__ Ob, const float2* __restrict__ wos,
                            float2* __restrict__ Xc, int m0, size_t mstride){
  int ml = blockIdx.y;
  int m = m0 + ml;
  const float2* O = Ob + (size_t)ml*mstride;
  const float2* Wo_ = wos + (size_t)m*Dn*Dn;
  int seg = m;
  int bx = blockIdx.x;
  int lt = bx & 3, dt = (bx >> 2) & 7, b = bx >> 5;
  int l0 = lt*64, d0 = dt*32;
  __shared__ float2 Os[16][65];
  __shared__ float2 Ws[16][32];
  int tid = threadIdx.x;
  int tx = tid & 15, ty = tid >> 4;
  float2 acc[2][4];
  #pragma unroll
  for (int k = 0; k < 2; ++k)
    #pragma unroll
    for (int j = 0; j < 4; ++j) acc[k][j] = make_float2(0.f, 0.f);
  for (int e0 = 0; e0 < Dn; e0 += 16){
    for (int j = tid; j < 16*64; j += 256){
      int ll = j >> 4, ee = j & 15;
      Os[ee][ll] = O[((size_t)(b*Ln + l0 + ll))*Dn + e0 + ee];
    }
    for (int j = tid; j < 16*32; j += 256){
      int ee = j >> 5, dd = j & 31;
      Ws[ee][dd] = Wo_[(size_t)(e0 + ee)*Dn + d0 + dd];
    }
    __syncthreads();
    #pragma unroll
    for (int ee = 0; ee < 16; ++ee){
      float2 a[4], w[2];
      #pragma unroll
      for (int j = 0; j < 4; ++j) a[j] = Os[ee][tx + j*16];
      #pragma unroll
      for (int k = 0; k < 2; ++k) w[k] = Ws[ee][ty*2 + k];
      #pragma unroll
      for (int k = 0; k < 2; ++k)
        #pragma unroll
        for (int j = 0; j < 4; ++j) acc[k][j] = cfma(a[j], w[k], acc[k][j]);
    }
    __syncthreads();
  }
  #pragma unroll
  for (int k = 0; k < 2; ++k)
    #pragma unroll
    for (int j = 0; j < 4; ++j)
      Xc[((size_t)(b*Dn + d0 + ty*2 + k))*L4n + seg*Ln + l0 + tx + j*16] = acc[k][j];
}

// mean over last dim (1024), one block per row
__global__ void row_mean_kernel(const float2* __restrict__ X, float2* __restrict__ y){
  int row = blockIdx.x;
  int tid = threadIdx.x;
  float sx = 0.f, sy = 0.f;
  const float2* xr = X + (size_t)row*L4n;
  for (int i = tid; i < L4n; i += 256){ float2 v = xr[i]; sx += v.x; sy += v.y; }
  __shared__ float rx[256], ry[256];
  rx[tid] = sx; ry[tid] = sy; __syncthreads();
  for (int st = 128; st > 0; st >>= 1){
    if (tid < st){ rx[tid] += rx[tid+st]; ry[tid] += ry[tid+st]; }
    __syncthreads();
  }
  if (tid == 0) y[row] = make_float2(rx[0]*(1.f/L4n), ry[0]*(1.f/L4n));
}

__global__ void eca_gate_kernel(const float2* __restrict__ y, const float2* __restrict__ w,
                                float2* __restrict__ g, int C){
  int idx = blockIdx.x*blockDim.x + threadIdx.x;
  if (idx >= Bn*C) return;
  int c = idx % C;
  int b = idx / C;
  float2 z = make_float2(0.f, 0.f);
  #pragma unroll
  for (int i = 0; i < KEn; ++i){
    int cc = c + i - 2;
    if (cc >= 0 && cc < C) z = cfma(w[i], y[b*C + cc], z);
  }
  g[idx] = make_float2(1.f/(1.f + expf(-z.x)), 1.f/(1.f + expf(-z.y)));
}

__global__ void eca_apply_kernel(float2* __restrict__ X, const float2* __restrict__ g){
  int idx = blockIdx.x*256 + threadIdx.x;
  int row = idx >> 10;
  X[idx] = cmul(X[idx], g[row]);
}

// ---------------- D x D x 3 conv over length 1024 ----------------
// out[b, ocoff+o, x] in a [B, ochans, 1024] tensor (writes straight into d_out).
// tile: 32 o x 64 x; K-chunk 16 channels.
__global__ void conv_dd_tiled(const float2* __restrict__ X, const float2* __restrict__ W,
                              float2* __restrict__ out, int ochans){
  __shared__ float2 Xs[16][66];
  __shared__ float2 Ws[32][49];
  int bx = blockIdx.x;
  int xt = bx & 15, ot = (bx >> 4) & 7, b = bx >> 7;
  int x0 = xt*64, o0 = ot*32;
  int tid = threadIdx.x;
  int tx = tid & 15, ty = tid >> 4;
  float2 acc[2][4];
  #pragma unroll
  for (int k = 0; k < 2; ++k)
    #pragma unroll
    for (int j = 0; j < 4; ++j) acc[k][j] = make_float2(0.f, 0.f);
  const float2* xb = X + (size_t)b*Dn*L4n;
  for (int c0 = 0; c0 < Dn; c0 += 16){
    for (int j = tid; j < 16*66; j += 256){
      int cc = j / 66, xx = j - cc*66;
      int gx = x0 + xx - 1;
      float2 v = make_float2(0.f, 0.f);
      if (gx >= 0 && gx < L4n) v = xb[(size_t)(c0 + cc)*L4n + gx];
      Xs[cc][xx] = v;
    }
    for (int j = tid; j < 32*48; j += 256){
      int o = j / 48, r = j - o*48;
      Ws[o][r] = W[(size_t)(o0 + o)*Dn*KWn + c0*KWn + r];
    }
    __syncthreads();
    #pragma unroll
    for (int cc = 0; cc < 16; ++cc){
      float2 xv[4][3];
      #pragma unroll
      for (int j = 0; j < 4; ++j)
        #pragma unroll
        for (int i = 0; i < 3; ++i) xv[j][i] = Xs[cc][tx + j*16 + i];
      #pragma unroll
      for (int k = 0; k < 2; ++k){
        float2 w0 = Ws[ty*2 + k][cc*3 + 0];
        float2 w1 = Ws[ty*2 + k][cc*3 + 1];
        float2 w2 = Ws[ty*2 + k][cc*3 + 2];
        #pragma unroll
        for (int j = 0; j < 4; ++j){
          acc[k][j] = cfma(xv[j][0], w0, acc[k][j]);
          acc[k][j] = cfma(xv[j][1], w1, acc[k][j]);
          acc[k][j] = cfma(xv[j][2], w2, acc[k][j]);
        }
      }
    }
    __syncthreads();
  }
  #pragma unroll
  for (int k = 0; k < 2; ++k)
    #pragma unroll
    for (int j = 0; j < 4; ++j)
      out[((size_t)(b*ochans + o0 + ty*2 + k))*L4n + x0 + tx + j*16] = acc[k][j];
}

} // namespace

extern "C" void kernel_launch(void* const* d_in, const int* in_sizes, int n_in,
                              void* d_out, int out_size, void* d_ws, size_t ws_size,
                              hipStream_t stream){
  const float2* X1 = (const float2*)d_in[0];
  const float2* X2 = (const float2*)d_in[1];
  const float2* head_w = (const float2*)d_in[2];
  const float2* head_b = (const float2*)d_in[3];
  const float2* wq = (const float2*)d_in[4];
  const float2* wk = (const float2*)d_in[5];
  const float2* wv = (const float2*)d_in[6];
  const float2* wo = (const float2*)d_in[7];
  const float2* se = (const float2*)d_in[8];
  const float2* sc = (const float2*)d_in[9];
  const float2* te = (const float2*)d_in[10];

  const size_t SZ_BDL = (size_t)Bn*Dn*Ln;      // 524288 complex = 4 MB
  const size_t SZ_X   = (size_t)Bn*Dn*L4n;     // 16 MB
  const size_t small  = 2*(size_t)Bn*2*Dn;

  // pick how many attention branches we can batch per launch
  int mcount = 1;
  {
    size_t need4 = ((size_t)4 + 16)*SZ_BDL + SZ_X + small;
    size_t need2 = ((size_t)4 + 8)*SZ_BDL + SZ_X + small;
    if (ws_size >= need4*sizeof(float2)) mcount = 4;
    else if (ws_size >= need2*sizeof(float2)) mcount = 2;
  }

  float2* p = (float2*)d_ws;
  float2* A  = p;  p += SZ_BDL;
  float2* Bc = p;  p += SZ_BDL;
  float2* iA = p;  p += SZ_BDL;
  float2* iB = p;  p += SZ_BDL;
  float2* Qb = p;  p += (size_t)mcount*SZ_BDL;
  float2* Kb = p;  p += (size_t)mcount*SZ_BDL;
  float2* Vb = p;  p += (size_t)mcount*SZ_BDL;
  float2* Ob = p;  p += (size_t)mcount*SZ_BDL;
  float2* Xc = p;  p += SZ_X;
  float2* ybuf = p; p += (size_t)Bn*2*Dn;
  float2* gbuf = p; p += (size_t)Bn*2*Dn;

  float2* out0 = (float2*)d_out;                   // [B, 512, 1024]
  float2* out1 = out0 + (size_t)Bn*2*Dn*L4n;

  head_conv_kernel<<<(Bn*Dn*Ln)/256, 256, 0, stream>>>(X1, head_w, head_b, A);
  head_conv_kernel<<<(Bn*Dn*Ln)/256, 256, 0, stream>>>(
      X2, head_w + (size_t)Dn*CINn*KWn, head_b + Dn, Bc);

  fft_rows_kernel<256,8><<<Bn*Dn, 256, 0, stream>>>(A,  iA, 256,0,256,0, 1.0f, 1.0f/256.0f);
  fft_rows_kernel<256,8><<<Bn*Dn, 256, 0, stream>>>(Bc, iB, 256,0,256,0, 1.0f, 1.0f/256.0f);

  auto run_ssca = [&](const float2* Ap, const float2* Bp, int set, float2* dstbase){
    const float2* wq_s = wq + (size_t)set*4*Dn*Dn;
    const float2* wk_s = wk + (size_t)set*4*Dn*Dn;
    const float2* wv_s = wv + (size_t)set*4*Dn*Dn;
    const float2* wo_s = wo + (size_t)set*4*Dn*Dn;
    for (int m0 = 0; m0 < 4; m0 += mcount){
      qkv_proj_kernel<<<dim3(Bn*16, 3*mcount), 256, 0, stream>>>(
          Ap, Bp, wq_s, wk_s, wv_s, Qb, Kb, Vb, m0, SZ_BDL);
      attn_fused_kernel<<<dim3(Bn*Hn*Ln, mcount), 256, 0, stream>>>(Qb, Kb, Vb, Ob, SZ_BDL);
      wo_xc_tiled<<<dim3(Bn*32, mcount), 256, 0, stream>>>(Ob, wo_s, Xc, m0, SZ_BDL);
    }
    row_mean_kernel<<<Bn*Dn, 256, 0, stream>>>(Xc, ybuf);
    eca_gate_kernel<<<(Bn*Dn + 255)/256, 256, 0, stream>>>(ybuf, se + set*KEn, gbuf, Dn);
    eca_apply_kernel<<<(int)(SZ_X/256), 256, 0, stream>>>(Xc, gbuf);
    conv_dd_tiled<<<Bn*128, 256, 0, stream>>>(Xc, sc + (size_t)set*Dn*Dn*KWn, dstbase, 2*Dn);
  };

  run_ssca(A,  Bc, 0, out0);   // R  -> out0 channels [0,256)
  run_ssca(iA, iB, 1, out1);   // kk -> out1 channels [0,256)

  // R2[:,256:] = fft(kk) ; k2[:,256:] = ifft(R)
  fft_rows_kernel<1024,10><<<Bn*Dn, 256, 0, stream>>>(out1, out0, 2*Dn,0, 2*Dn,Dn, -1.0f, 1.0f);
  fft_rows_kernel<1024,10><<<Bn*Dn, 256, 0, stream>>>(out0, out1, 2*Dn,0, 2*Dn,Dn, 1.0f, 1.0f/1024.0f);

  for (int t = 0; t < 2; ++t){
    float2* op = (t == 0) ? out0 : out1;
    row_mean_kernel<<<Bn*2*Dn, 256, 0, stream>>>(op, ybuf);
    eca_gate_kernel<<<(Bn*2*Dn + 255)/256, 256, 0, stream>>>(ybuf, te + t*KEn, gbuf, 2*Dn);
    eca_apply_kernel<<<(Bn*2*Dn*L4n)/256, 256, 0, stream>>>(op, gbuf);
  }
}

// Round 4
// 1463.368 us; speedup vs baseline: 3.1230x; 1.5895x over previous
//
#include <hip/hip_runtime.h>
#include <math.h>

namespace {

constexpr int Bn = 8, CINn = 16, Ln = 256, Dn = 256, Hn = 8, DKn = 32, DVn = 32;
constexpr int KWn = 3, KEn = 5, L4n = 1024;
constexpr float EPSf = 1e-9f;

__device__ __forceinline__ float2 cmul(float2 a, float2 b){
  return make_float2(a.x*b.x - a.y*b.y, a.x*b.y + a.y*b.x);
}
__device__ __forceinline__ float2 cfma(float2 a, float2 b, float2 c){
  c.x = fmaf(a.x, b.x, c.x); c.x = fmaf(-a.y, b.y, c.x);
  c.y = fmaf(a.x, b.y, c.y); c.y = fmaf(a.y, b.x, c.y);
  return c;
}

// A[b,o,l] = sum_c sum_i X[b,c,l+i-1] * hw[o,c,i] + hb[o]
__global__ void head_conv_kernel(const float2* __restrict__ X, const float2* __restrict__ hw,
                                 const float2* __restrict__ hb, float2* __restrict__ out){
  int idx = blockIdx.x * blockDim.x + threadIdx.x;
  if (idx >= Bn*Dn*Ln) return;
  int l = idx & (Ln-1);
  int o = (idx >> 8) & (Dn-1);
  int b = idx >> 16;
  float2 acc = hb[o];
  for (int c = 0; c < CINn; ++c){
    const float2* xr = X + (size_t)(b*CINn + c)*Ln;
    const float2* wr = hw + (size_t)(o*CINn + c)*KWn;
    #pragma unroll
    for (int i = 0; i < KWn; ++i){
      int ll = l + i - 1;
      if (ll >= 0 && ll < Ln) acc = cfma(xr[ll], wr[i], acc);
    }
  }
  out[idx] = acc;
}

// In-LDS radix-2 FFT with twiddle table; rows mapped through (chans, coff).
template<int N, int LOG>
__global__ void fft_rows_kernel(const float2* __restrict__ src0, float2* __restrict__ dst0,
                                int schans, int scoff, int dchans, int dcoff,
                                float sign, float scale){
  __shared__ float2 buf[N];
  __shared__ float2 tw[N/2];
  int row = blockIdx.x;
  int rb = row >> 8, rc = row & 255;
  const float2* src = src0 + (size_t)(rb*schans + scoff + rc)*N;
  float2* dst = dst0 + (size_t)(rb*dchans + dcoff + rc)*N;
  int tid = threadIdx.x;
  for (int i = tid; i < N/2; i += 256){
    float a = sign * 6.2831853071795864f * (float)i / (float)N;
    float s, c; __sincosf(a, &s, &c);
    tw[i] = make_float2(c, s);
  }
  for (int i = tid; i < N; i += 256){
    unsigned r = __brev((unsigned)i) >> (32 - LOG);
    buf[r] = src[i];
  }
  __syncthreads();
  for (int st = 1; st <= LOG; ++st){
    int half = 1 << (st-1);
    for (int bf = tid; bf < N/2; bf += 256){
      int blk = bf >> (st-1);
      int pos = bf & (half-1);
      int i0 = (blk << st) + pos;
      int i1 = i0 + half;
      float2 w = tw[pos << (LOG-st)];
      float2 u = buf[i0];
      float2 t = cmul(w, buf[i1]);
      buf[i0] = make_float2(u.x + t.x, u.y + t.y);
      buf[i1] = make_float2(u.x - t.x, u.y - t.y);
    }
    __syncthreads();
  }
  for (int i = tid; i < N; i += 256)
    dst[i] = make_float2(buf[i].x * scale, buf[i].y * scale);
}

// ---------------- fused QKV projection for mcount m's in one launch ----------
__global__ void qkv_proj_kernel(const float2* __restrict__ Ap, const float2* __restrict__ Bp,
                                const float2* __restrict__ wqs, const float2* __restrict__ wks,
                                const float2* __restrict__ wvs,
                                float2* __restrict__ Qb, float2* __restrict__ Kb,
                                float2* __restrict__ Vb, int m0, size_t mstride){
  int my = blockIdx.y;
  int ml = my / 3, which = my - ml*3;
  int m = m0 + ml;
  const float2* Ain;
  if (which == 0) Ain = (m == 0 || m == 2) ? Ap : Bp;   // qin
  else            Ain = (m == 0 || m == 3) ? Ap : Bp;   // kvin
  const float2* W = ((which == 0) ? wqs : (which == 1) ? wks : wvs) + (size_t)m*Dn*Dn;
  float2* Out = ((which == 0) ? Qb : (which == 1) ? Kb : Vb) + (size_t)ml*mstride;
  int bx = blockIdx.x;
  int et = bx & 3, lt = (bx >> 2) & 3, b = bx >> 4;
  int l0 = lt*64, e0 = et*64;
  __shared__ float2 As[16][64];
  __shared__ float2 Ws[16][64];
  int tid = threadIdx.x;
  int tx = tid & 15, ty = tid >> 4;
  float2 acc[4][4];
  #pragma unroll
  for (int k = 0; k < 4; ++k)
    #pragma unroll
    for (int j = 0; j < 4; ++j) acc[k][j] = make_float2(0.f, 0.f);
  for (int d0 = 0; d0 < Dn; d0 += 16){
    for (int j = tid; j < 16*64; j += 256){
      int dd = j >> 6, ll = j & 63;
      As[dd][ll] = Ain[((size_t)b*Dn + d0 + dd)*Ln + l0 + ll];
    }
    for (int j = tid; j < 16*64; j += 256){
      int dd = j >> 6, ee = j & 63;
      Ws[dd][ee] = W[(size_t)(d0 + dd)*Dn + e0 + ee];
    }
    __syncthreads();
    #pragma unroll
    for (int dd = 0; dd < 16; ++dd){
      float2 a[4], w[4];
      #pragma unroll
      for (int k = 0; k < 4; ++k) a[k] = As[dd][ty*4 + k];
      #pragma unroll
      for (int j = 0; j < 4; ++j) w[j] = Ws[dd][tx + j*16];
      #pragma unroll
      for (int k = 0; k < 4; ++k)
        #pragma unroll
        for (int j = 0; j < 4; ++j) acc[k][j] = cfma(a[k], w[j], acc[k][j]);
    }
    __syncthreads();
  }
  #pragma unroll
  for (int k = 0; k < 4; ++k)
    #pragma unroll
    for (int j = 0; j < 4; ++j)
      Out[((size_t)(b*Ln + l0 + ty*4 + k))*Dn + e0 + tx + j*16] = acc[k][j];
}

// ---------------- fused attention, q-tiled flash-style ----------------
// Block = (b, h, 16-q tile); blockIdx.y = ml. Threads 256 = 16 qq x 16 ks.
// Phase 1: S = scaled Q K^T into LDS Ps (thread: 16 scores, runtime chunks).
// Phase 2: row min/max via 16-lane shfl; normalize own entries in place.
// Phase 3: O[qq][ks*2 .. +1] = sum_k Ps[qq][k] * V[k][dv], V chunks in LDS.
__global__ void attn_fused_kernel(const float2* __restrict__ Qb, const float2* __restrict__ Kb,
                                  const float2* __restrict__ Vb, float2* __restrict__ Ob,
                                  size_t mstride){
  const float2* Q = Qb + (size_t)blockIdx.y*mstride;
  const float2* K = Kb + (size_t)blockIdx.y*mstride;
  const float2* V = Vb + (size_t)blockIdx.y*mstride;
  float2* O = Ob + (size_t)blockIdx.y*mstride;
  int bx = blockIdx.x;
  int qt = bx & 15, h = (bx >> 4) & 7, b = bx >> 7;
  int q0 = qt*16;
  int tid = threadIdx.x;
  int qq = tid >> 4, ks = tid & 15;
  __shared__ float2 Qs[16][34];
  __shared__ float2 Ks[32][34];     // K chunk; reused as V chunk in phase 3
  __shared__ float2 Ps[16][257];
  const float scl = 0.17677669529663687f;   // 1/sqrt(32)
  for (int j = tid; j < 16*32; j += 256){
    int r = j >> 5, c = j & 31;
    float2 v = Q[((size_t)(b*Ln + q0 + r))*Dn + h*DKn + c];
    Qs[r][c] = make_float2(v.x*scl, v.y*scl);
  }
  float mn = 3.4e38f, mx = 0.f;
  for (int kc = 0; kc < 8; ++kc){
    __syncthreads();
    for (int j = tid; j < 32*32; j += 256){
      int r = j >> 5, c = j & 31;
      Ks[r][c] = K[((size_t)(b*Ln + kc*32 + r))*Dn + h*DKn + c];
    }
    __syncthreads();
    #pragma unroll
    for (int j2 = 0; j2 < 2; ++j2){
      int kl = ks + 16*j2;
      float2 acc = make_float2(0.f, 0.f);
      #pragma unroll
      for (int d = 0; d < 32; ++d)
        acc = cfma(Qs[qq][d], Ks[kl][d], acc);
      float mag = sqrtf(acc.x*acc.x + acc.y*acc.y);
      mn = fminf(mn, mag); mx = fmaxf(mx, mag);
      Ps[qq][kc*32 + kl] = acc;
    }
  }
  #pragma unroll
  for (int off = 1; off < 16; off <<= 1){
    mn = fminf(mn, __shfl_xor(mn, off));
    mx = fmaxf(mx, __shfl_xor(mx, off));
  }
  float inv = 1.0f/(mx - mn + EPSf);
  #pragma unroll
  for (int kc = 0; kc < 8; ++kc)
    #pragma unroll
    for (int j2 = 0; j2 < 2; ++j2){
      int k = kc*32 + ks + 16*j2;
      float2 sv = Ps[qq][k];
      float mag = sqrtf(sv.x*sv.x + sv.y*sv.y);
      float f = ((mag - mn)*inv)/(mag + EPSf);
      Ps[qq][k] = make_float2(sv.x*f, sv.y*f);
    }
  float2 o0 = make_float2(0.f, 0.f), o1 = make_float2(0.f, 0.f);
  for (int kc = 0; kc < 8; ++kc){
    __syncthreads();
    for (int j = tid; j < 32*32; j += 256){
      int r = j >> 5, c = j & 31;
      Ks[r][c] = V[((size_t)(b*Ln + kc*32 + r))*Dn + h*DVn + c];
    }
    __syncthreads();
    #pragma unroll 4
    for (int kk = 0; kk < 32; ++kk){
      float2 pv = Ps[qq][kc*32 + kk];
      o0 = cfma(pv, Ks[kk][ks*2 + 0], o0);
      o1 = cfma(pv, Ks[kk][ks*2 + 1], o1);
    }
  }
  float2* orow = O + ((size_t)(b*Ln + q0 + qq))*Dn + h*DVn + ks*2;
  orow[0] = o0; orow[1] = o1;
}

// ---------------- Wo projection into Xc ----------------
__global__ void wo_xc_tiled(const float2* __restrict__ Ob, const float2* __restrict__ wos,
                            float2* __restrict__ Xc, int m0, size_t mstride){
  int ml = blockIdx.y;
  int m = m0 + ml;
  const float2* O = Ob + (size_t)ml*mstride;
  const float2* Wo_ = wos + (size_t)m*Dn*Dn;
  int seg = m;
  int bx = blockIdx.x;
  int lt = bx & 3, dt = (bx >> 2) & 7, b = bx >> 5;
  int l0 = lt*64, d0 = dt*32;
  __shared__ float2 Os[16][65];
  __shared__ float2 Ws[16][32];
  int tid = threadIdx.x;
  int tx = tid & 15, ty = tid >> 4;
  float2 acc[2][4];
  #pragma unroll
  for (int k = 0; k < 2; ++k)
    #pragma unroll
    for (int j = 0; j < 4; ++j) acc[k][j] = make_float2(0.f, 0.f);
  for (int e0 = 0; e0 < Dn; e0 += 16){
    for (int j = tid; j < 16*64; j += 256){
      int ll = j >> 4, ee = j & 15;
      Os[ee][ll] = O[((size_t)(b*Ln + l0 + ll))*Dn + e0 + ee];
    }
    for (int j = tid; j < 16*32; j += 256){
      int ee = j >> 5, dd = j & 31;
      Ws[ee][dd] = Wo_[(size_t)(e0 + ee)*Dn + d0 + dd];
    }
    __syncthreads();
    #pragma unroll
    for (int ee = 0; ee < 16; ++ee){
      float2 a[4], w[2];
      #pragma unroll
      for (int j = 0; j < 4; ++j) a[j] = Os[ee][tx + j*16];
      #pragma unroll
      for (int k = 0; k < 2; ++k) w[k] = Ws[ee][ty*2 + k];
      #pragma unroll
      for (int k = 0; k < 2; ++k)
        #pragma unroll
        for (int j = 0; j < 4; ++j) acc[k][j] = cfma(a[j], w[k], acc[k][j]);
    }
    __syncthreads();
  }
  #pragma unroll
  for (int k = 0; k < 2; ++k)
    #pragma unroll
    for (int j = 0; j < 4; ++j)
      Xc[((size_t)(b*Dn + d0 + ty*2 + k))*L4n + seg*Ln + l0 + tx + j*16] = acc[k][j];
}

// mean over last dim (1024), one block per row
__global__ void row_mean_kernel(const float2* __restrict__ X, float2* __restrict__ y){
  int row = blockIdx.x;
  int tid = threadIdx.x;
  float sx = 0.f, sy = 0.f;
  const float2* xr = X + (size_t)row*L4n;
  for (int i = tid; i < L4n; i += 256){ float2 v = xr[i]; sx += v.x; sy += v.y; }
  __shared__ float rx[256], ry[256];
  rx[tid] = sx; ry[tid] = sy; __syncthreads();
  for (int st = 128; st > 0; st >>= 1){
    if (tid < st){ rx[tid] += rx[tid+st]; ry[tid] += ry[tid+st]; }
    __syncthreads();
  }
  if (tid == 0) y[row] = make_float2(rx[0]*(1.f/L4n), ry[0]*(1.f/L4n));
}

__global__ void eca_gate_kernel(const float2* __restrict__ y, const float2* __restrict__ w,
                                float2* __restrict__ g, int C){
  int idx = blockIdx.x*blockDim.x + threadIdx.x;
  if (idx >= Bn*C) return;
  int c = idx % C;
  int b = idx / C;
  float2 z = make_float2(0.f, 0.f);
  #pragma unroll
  for (int i = 0; i < KEn; ++i){
    int cc = c + i - 2;
    if (cc >= 0 && cc < C) z = cfma(w[i], y[b*C + cc], z);
  }
  g[idx] = make_float2(1.f/(1.f + expf(-z.x)), 1.f/(1.f + expf(-z.y)));
}

__global__ void eca_apply_kernel(float2* __restrict__ X, const float2* __restrict__ g){
  int idx = blockIdx.x*256 + threadIdx.x;
  int row = idx >> 10;
  X[idx] = cmul(X[idx], g[row]);
}

// ---------------- D x D x 3 conv over length 1024 ----------------
__global__ void conv_dd_tiled(const float2* __restrict__ X, const float2* __restrict__ W,
                              float2* __restrict__ out, int ochans){
  __shared__ float2 Xs[16][66];
  __shared__ float2 Ws[32][49];
  int bx = blockIdx.x;
  int xt = bx & 15, ot = (bx >> 4) & 7, b = bx >> 7;
  int x0 = xt*64, o0 = ot*32;
  int tid = threadIdx.x;
  int tx = tid & 15, ty = tid >> 4;
  float2 acc[2][4];
  #pragma unroll
  for (int k = 0; k < 2; ++k)
    #pragma unroll
    for (int j = 0; j < 4; ++j) acc[k][j] = make_float2(0.f, 0.f);
  const float2* xb = X + (size_t)b*Dn*L4n;
  for (int c0 = 0; c0 < Dn; c0 += 16){
    for (int j = tid; j < 16*66; j += 256){
      int cc = j / 66, xx = j - cc*66;
      int gx = x0 + xx - 1;
      float2 v = make_float2(0.f, 0.f);
      if (gx >= 0 && gx < L4n) v = xb[(size_t)(c0 + cc)*L4n + gx];
      Xs[cc][xx] = v;
    }
    for (int j = tid; j < 32*48; j += 256){
      int o = j / 48, r = j - o*48;
      Ws[o][r] = W[(size_t)(o0 + o)*Dn*KWn + c0*KWn + r];
    }
    __syncthreads();
    #pragma unroll
    for (int cc = 0; cc < 16; ++cc){
      float2 xv[4][3];
      #pragma unroll
      for (int j = 0; j < 4; ++j)
        #pragma unroll
        for (int i = 0; i < 3; ++i) xv[j][i] = Xs[cc][tx + j*16 + i];
      #pragma unroll
      for (int k = 0; k < 2; ++k){
        float2 w0 = Ws[ty*2 + k][cc*3 + 0];
        float2 w1 = Ws[ty*2 + k][cc*3 + 1];
        float2 w2 = Ws[ty*2 + k][cc*3 + 2];
        #pragma unroll
        for (int j = 0; j < 4; ++j){
          acc[k][j] = cfma(xv[j][0], w0, acc[k][j]);
          acc[k][j] = cfma(xv[j][1], w1, acc[k][j]);
          acc[k][j] = cfma(xv[j][2], w2, acc[k][j]);
        }
      }
    }
    __syncthreads();
  }
  #pragma unroll
  for (int k = 0; k < 2; ++k)
    #pragma unroll
    for (int j = 0; j < 4; ++j)
      out[((size_t)(b*ochans + o0 + ty*2 + k))*L4n + x0 + tx + j*16] = acc[k][j];
}

} // namespace

extern "C" void kernel_launch(void* const* d_in, const int* in_sizes, int n_in,
                              void* d_out, int out_size, void* d_ws, size_t ws_size,
                              hipStream_t stream){
  const float2* X1 = (const float2*)d_in[0];
  const float2* X2 = (const float2*)d_in[1];
  const float2* head_w = (const float2*)d_in[2];
  const float2* head_b = (const float2*)d_in[3];
  const float2* wq = (const float2*)d_in[4];
  const float2* wk = (const float2*)d_in[5];
  const float2* wv = (const float2*)d_in[6];
  const float2* wo = (const float2*)d_in[7];
  const float2* se = (const float2*)d_in[8];
  const float2* sc = (const float2*)d_in[9];
  const float2* te = (const float2*)d_in[10];

  const size_t SZ_BDL = (size_t)Bn*Dn*Ln;      // 524288 complex = 4 MB
  const size_t SZ_X   = (size_t)Bn*Dn*L4n;     // 16 MB
  const size_t small  = 2*(size_t)Bn*2*Dn;

  int mcount = 1;
  {
    size_t need4 = ((size_t)4 + 16)*SZ_BDL + SZ_X + small;
    size_t need2 = ((size_t)4 + 8)*SZ_BDL + SZ_X + small;
    if (ws_size >= need4*sizeof(float2)) mcount = 4;
    else if (ws_size >= need2*sizeof(float2)) mcount = 2;
  }

  float2* p = (float2*)d_ws;
  float2* A  = p;  p += SZ_BDL;
  float2* Bc = p;  p += SZ_BDL;
  float2* iA = p;  p += SZ_BDL;
  float2* iB = p;  p += SZ_BDL;
  float2* Qb = p;  p += (size_t)mcount*SZ_BDL;
  float2* Kb = p;  p += (size_t)mcount*SZ_BDL;
  float2* Vb = p;  p += (size_t)mcount*SZ_BDL;
  float2* Ob = p;  p += (size_t)mcount*SZ_BDL;
  float2* Xc = p;  p += SZ_X;
  float2* ybuf = p; p += (size_t)Bn*2*Dn;
  float2* gbuf = p; p += (size_t)Bn*2*Dn;

  float2* out0 = (float2*)d_out;                   // [B, 512, 1024]
  float2* out1 = out0 + (size_t)Bn*2*Dn*L4n;

  head_conv_kernel<<<(Bn*Dn*Ln)/256, 256, 0, stream>>>(X1, head_w, head_b, A);
  head_conv_kernel<<<(Bn*Dn*Ln)/256, 256, 0, stream>>>(
      X2, head_w + (size_t)Dn*CINn*KWn, head_b + Dn, Bc);

  fft_rows_kernel<256,8><<<Bn*Dn, 256, 0, stream>>>(A,  iA, 256,0,256,0, 1.0f, 1.0f/256.0f);
  fft_rows_kernel<256,8><<<Bn*Dn, 256, 0, stream>>>(Bc, iB, 256,0,256,0, 1.0f, 1.0f/256.0f);

  auto run_ssca = [&](const float2* Ap, const float2* Bp, int set, float2* dstbase){
    const float2* wq_s = wq + (size_t)set*4*Dn*Dn;
    const float2* wk_s = wk + (size_t)set*4*Dn*Dn;
    const float2* wv_s = wv + (size_t)set*4*Dn*Dn;
    const float2* wo_s = wo + (size_t)set*4*Dn*Dn;
    for (int m0 = 0; m0 < 4; m0 += mcount){
      qkv_proj_kernel<<<dim3(Bn*16, 3*mcount), 256, 0, stream>>>(
          Ap, Bp, wq_s, wk_s, wv_s, Qb, Kb, Vb, m0, SZ_BDL);
      attn_fused_kernel<<<dim3(Bn*Hn*16, mcount), 256, 0, stream>>>(Qb, Kb, Vb, Ob, SZ_BDL);
      wo_xc_tiled<<<dim3(Bn*32, mcount), 256, 0, stream>>>(Ob, wo_s, Xc, m0, SZ_BDL);
    }
    row_mean_kernel<<<Bn*Dn, 256, 0, stream>>>(Xc, ybuf);
    eca_gate_kernel<<<(Bn*Dn + 255)/256, 256, 0, stream>>>(ybuf, se + set*KEn, gbuf, Dn);
    eca_apply_kernel<<<(int)(SZ_X/256), 256, 0, stream>>>(Xc, gbuf);
    conv_dd_tiled<<<Bn*128, 256, 0, stream>>>(Xc, sc + (size_t)set*Dn*Dn*KWn, dstbase, 2*Dn);
  };

  run_ssca(A,  Bc, 0, out0);   // R  -> out0 channels [0,256)
  run_ssca(iA, iB, 1, out1);   // kk -> out1 channels [0,256)

  // R2[:,256:] = fft(kk) ; k2[:,256:] = ifft(R)
  fft_rows_kernel<1024,10><<<Bn*Dn, 256, 0, stream>>>(out1, out0, 2*Dn,0, 2*Dn,Dn, -1.0f, 1.0f);
  fft_rows_kernel<1024,10><<<Bn*Dn, 256, 0, stream>>>(out0, out1, 2*Dn,0, 2*Dn,Dn, 1.0f, 1.0f/1024.0f);

  for (int t = 0; t < 2; ++t){
    float2* op = (t == 0) ? out0 : out1;
    row_mean_kernel<<<Bn*2*Dn, 256, 0, stream>>>(op, ybuf);
    eca_gate_kernel<<<(Bn*2*Dn + 255)/256, 256, 0, stream>>>(ybuf, te + t*KEn, gbuf, 2*Dn);
    eca_apply_kernel<<<(Bn*2*Dn*L4n)/256, 256, 0, stream>>>(op, gbuf);
  }
}

// Round 5
// 1285.308 us; speedup vs baseline: 3.5557x; 1.1385x over previous
//
#include <hip/hip_runtime.h>
#include <math.h>

namespace {

constexpr int Bn = 8, CINn = 16, Ln = 256, Dn = 256, Hn = 8, DKn = 32, DVn = 32;
constexpr int KWn = 3, KEn = 5, L4n = 1024;
constexpr float EPSf = 1e-9f;

__device__ __forceinline__ float2 cmul(float2 a, float2 b){
  return make_float2(a.x*b.x - a.y*b.y, a.x*b.y + a.y*b.x);
}
__device__ __forceinline__ float2 cfma(float2 a, float2 b, float2 c){
  c.x = fmaf(a.x, b.x, c.x); c.x = fmaf(-a.y, b.y, c.x);
  c.y = fmaf(a.x, b.y, c.y); c.y = fmaf(a.y, b.x, c.y);
  return c;
}

// A[b,o,l] = sum_c sum_i X[b,c,l+i-1] * hw[o,c,i] + hb[o]
__global__ void head_conv_kernel(const float2* __restrict__ X, const float2* __restrict__ hw,
                                 const float2* __restrict__ hb, float2* __restrict__ out){
  int idx = blockIdx.x * blockDim.x + threadIdx.x;
  if (idx >= Bn*Dn*Ln) return;
  int l = idx & (Ln-1);
  int o = (idx >> 8) & (Dn-1);
  int b = idx >> 16;
  float2 acc = hb[o];
  for (int c = 0; c < CINn; ++c){
    const float2* xr = X + (size_t)(b*CINn + c)*Ln;
    const float2* wr = hw + (size_t)(o*CINn + c)*KWn;
    #pragma unroll
    for (int i = 0; i < KWn; ++i){
      int ll = l + i - 1;
      if (ll >= 0 && ll < Ln) acc = cfma(xr[ll], wr[i], acc);
    }
  }
  out[idx] = acc;
}

// In-LDS radix-2 FFT with twiddle table; rows mapped through (chans, coff).
template<int N, int LOG>
__global__ void fft_rows_kernel(const float2* __restrict__ src0, float2* __restrict__ dst0,
                                int schans, int scoff, int dchans, int dcoff,
                                float sign, float scale){
  __shared__ float2 buf[N];
  __shared__ float2 tw[N/2];
  int row = blockIdx.x;
  int rb = row >> 8, rc = row & 255;
  const float2* src = src0 + (size_t)(rb*schans + scoff + rc)*N;
  float2* dst = dst0 + (size_t)(rb*dchans + dcoff + rc)*N;
  int tid = threadIdx.x;
  for (int i = tid; i < N/2; i += 256){
    float a = sign * 6.2831853071795864f * (float)i / (float)N;
    float s, c; __sincosf(a, &s, &c);
    tw[i] = make_float2(c, s);
  }
  for (int i = tid; i < N; i += 256){
    unsigned r = __brev((unsigned)i) >> (32 - LOG);
    buf[r] = src[i];
  }
  __syncthreads();
  for (int st = 1; st <= LOG; ++st){
    int half = 1 << (st-1);
    for (int bf = tid; bf < N/2; bf += 256){
      int blk = bf >> (st-1);
      int pos = bf & (half-1);
      int i0 = (blk << st) + pos;
      int i1 = i0 + half;
      float2 w = tw[pos << (LOG-st)];
      float2 u = buf[i0];
      float2 t = cmul(w, buf[i1]);
      buf[i0] = make_float2(u.x + t.x, u.y + t.y);
      buf[i1] = make_float2(u.x - t.x, u.y - t.y);
    }
    __syncthreads();
  }
  for (int i = tid; i < N; i += 256)
    dst[i] = make_float2(buf[i].x * scale, buf[i].y * scale);
}

// ---------------- fused QKV projection for mcount m's in one launch ----------
// Q,V: Out[b,l,e].  K: stored TRANSPOSED -> KT[(b*D + e)*L + l] for attn phase 1.
__global__ void qkv_proj_kernel(const float2* __restrict__ Ap, const float2* __restrict__ Bp,
                                const float2* __restrict__ wqs, const float2* __restrict__ wks,
                                const float2* __restrict__ wvs,
                                float2* __restrict__ Qb, float2* __restrict__ Kb,
                                float2* __restrict__ Vb, int m0, size_t mstride){
  int my = blockIdx.y;
  int ml = my / 3, which = my - ml*3;
  int m = m0 + ml;
  const float2* Ain;
  if (which == 0) Ain = (m == 0 || m == 2) ? Ap : Bp;   // qin
  else            Ain = (m == 0 || m == 3) ? Ap : Bp;   // kvin
  const float2* W = ((which == 0) ? wqs : (which == 1) ? wks : wvs) + (size_t)m*Dn*Dn;
  float2* Out = ((which == 0) ? Qb : (which == 1) ? Kb : Vb) + (size_t)ml*mstride;
  int bx = blockIdx.x;
  int et = bx & 3, lt = (bx >> 2) & 3, b = bx >> 4;
  int l0 = lt*64, e0 = et*64;
  __shared__ float2 As[16][64];
  __shared__ float2 Ws[16][64];
  int tid = threadIdx.x;
  int tx = tid & 15, ty = tid >> 4;
  float2 acc[4][4];
  #pragma unroll
  for (int k = 0; k < 4; ++k)
    #pragma unroll
    for (int j = 0; j < 4; ++j) acc[k][j] = make_float2(0.f, 0.f);
  for (int d0 = 0; d0 < Dn; d0 += 16){
    for (int j = tid; j < 16*64; j += 256){
      int dd = j >> 6, ll = j & 63;
      As[dd][ll] = Ain[((size_t)b*Dn + d0 + dd)*Ln + l0 + ll];
    }
    for (int j = tid; j < 16*64; j += 256){
      int dd = j >> 6, ee = j & 63;
      Ws[dd][ee] = W[(size_t)(d0 + dd)*Dn + e0 + ee];
    }
    __syncthreads();
    #pragma unroll
    for (int dd = 0; dd < 16; ++dd){
      float2 a[4], w[4];
      #pragma unroll
      for (int k = 0; k < 4; ++k) a[k] = As[dd][ty*4 + k];
      #pragma unroll
      for (int j = 0; j < 4; ++j) w[j] = Ws[dd][tx + j*16];
      #pragma unroll
      for (int k = 0; k < 4; ++k)
        #pragma unroll
        for (int j = 0; j < 4; ++j) acc[k][j] = cfma(a[k], w[j], acc[k][j]);
    }
    __syncthreads();
  }
  if (which == 1){
    #pragma unroll
    for (int k = 0; k < 4; ++k)
      #pragma unroll
      for (int j = 0; j < 4; ++j)
        Out[((size_t)(b*Dn + e0 + tx + j*16))*Ln + l0 + ty*4 + k] = acc[k][j];
  } else {
    #pragma unroll
    for (int k = 0; k < 4; ++k)
      #pragma unroll
      for (int j = 0; j < 4; ++j)
        Out[((size_t)(b*Ln + l0 + ty*4 + k))*Dn + e0 + tx + j*16] = acc[k][j];
  }
}

// ---------------- fused attention, register-centric ----------------
// Block = (b, h, 16-q tile); blockIdx.y = ml. 256 threads.
// Phase 1: thread = k column. KT rows streamed coalesced from global to regs;
//          Qs[q][d] LDS reads are full-wave broadcasts. acc[16] in registers.
// minmax:  scores -> Ps; 16-lane-group strided reduce + shfl; fmm in Qs col 32.
// Phase 3: thread = (kc,dv). V rows coalesced from global; Ps reads broadcast;
//          partial O[16] in regs; shfl_xor(32) + LDS tree over 8 kc groups.
__global__ void attn_fused_kernel(const float2* __restrict__ Qb, const float2* __restrict__ KTb,
                                  const float2* __restrict__ Vb, float2* __restrict__ Ob,
                                  size_t mstride){
  const float2* Q  = Qb  + (size_t)blockIdx.y*mstride;
  const float2* KT = KTb + (size_t)blockIdx.y*mstride;
  const float2* V  = Vb  + (size_t)blockIdx.y*mstride;
  float2* O = Ob + (size_t)blockIdx.y*mstride;
  int bx = blockIdx.x;
  int qt = bx & 15, h = (bx >> 4) & 7, b = bx >> 7;
  int q0 = qt*16;
  int tid = threadIdx.x;
  __shared__ float2 smem[528 + 4112];   // Qs[16][33] | Ps[16][257] (Ps reused as reduce buf)
  float2* Qs = smem;
  float2* Ps = smem + 528;
  const float scl = 0.17677669529663687f;   // 1/sqrt(32)
  for (int j = tid; j < 16*32; j += 256){
    int r = j >> 5, c = j & 31;
    float2 v = Q[((size_t)(b*Ln + q0 + r))*Dn + h*DKn + c];
    Qs[r*33 + c] = make_float2(v.x*scl, v.y*scl);
  }
  __syncthreads();
  // ---- phase 1: scores for k = tid ----
  float2 acc[16];
  #pragma unroll
  for (int q = 0; q < 16; ++q) acc[q] = make_float2(0.f, 0.f);
  const float2* ktbase = KT + ((size_t)(b*Dn + h*DKn))*Ln + tid;
  #pragma unroll
  for (int dc = 0; dc < 4; ++dc){
    float2 kreg[8];
    #pragma unroll
    for (int dd = 0; dd < 8; ++dd)
      kreg[dd] = ktbase[(size_t)(dc*8 + dd)*Ln];
    #pragma unroll
    for (int dd = 0; dd < 8; ++dd)
      #pragma unroll
      for (int q = 0; q < 16; ++q)
        acc[q] = cfma(Qs[q*33 + dc*8 + dd], kreg[dd], acc[q]);
  }
  #pragma unroll
  for (int q = 0; q < 16; ++q) Ps[q*257 + tid] = acc[q];
  __syncthreads();
  // ---- row min/max: thread (q = tid>>4, g = tid&15) ----
  {
    int q = tid >> 4, g = tid & 15;
    float mn = 3.4e38f, mx = 0.f;
    #pragma unroll
    for (int t = 0; t < 16; ++t){
      float2 s = Ps[q*257 + g + t*16];
      float m = sqrtf(s.x*s.x + s.y*s.y);
      mn = fminf(mn, m); mx = fmaxf(mx, m);
    }
    #pragma unroll
    for (int off = 1; off < 16; off <<= 1){
      mn = fminf(mn, __shfl_xor(mn, off));
      mx = fmaxf(mx, __shfl_xor(mx, off));
    }
    if (g == 0) Qs[q*33 + 32] = make_float2(mn, mx);
  }
  __syncthreads();
  // ---- normalize own scores (still in regs) and rewrite Ps ----
  #pragma unroll
  for (int q = 0; q < 16; ++q){
    float2 mm = Qs[q*33 + 32];
    float mag = sqrtf(acc[q].x*acc[q].x + acc[q].y*acc[q].y);
    float f = ((mag - mm.x) / (mm.y - mm.x + EPSf)) / (mag + EPSf);
    Ps[q*257 + tid] = make_float2(acc[q].x*f, acc[q].y*f);
  }
  __syncthreads();
  // ---- phase 3: thread = (kc = tid>>5, dv = tid&31) ----
  int kc = tid >> 5, dv = tid & 31;
  float2 oacc[16];
  #pragma unroll
  for (int q = 0; q < 16; ++q) oacc[q] = make_float2(0.f, 0.f);
  const float2* vbase = V + ((size_t)(b*Ln + kc*32))*Dn + h*DVn + dv;
  #pragma unroll 4
  for (int kk = 0; kk < 32; ++kk){
    float2 vv = vbase[(size_t)kk*Dn];
    int k = kc*32 + kk;
    #pragma unroll
    for (int q = 0; q < 16; ++q)
      oacc[q] = cfma(Ps[q*257 + k], vv, oacc[q]);
  }
  __syncthreads();                       // all Ps reads done; alias reduce buffer
  float2* buf = Ps;                      // [4][16][32]
  #pragma unroll
  for (int q = 0; q < 16; ++q){
    oacc[q].x += __shfl_xor(oacc[q].x, 32);
    oacc[q].y += __shfl_xor(oacc[q].y, 32);
  }
  int wv = tid >> 6, lane = tid & 63;
  if (lane < 32){
    #pragma unroll
    for (int q = 0; q < 16; ++q)
      buf[wv*512 + q*32 + dv] = oacc[q];
  }
  __syncthreads();
  #pragma unroll
  for (int half = 0; half < 2; ++half){
    int o = tid + half*256;
    int q = o >> 5, d = o & 31;
    float2 r = buf[o];
    #pragma unroll
    for (int w = 1; w < 4; ++w){
      float2 t = buf[w*512 + o];
      r.x += t.x; r.y += t.y;
    }
    O[((size_t)(b*Ln + q0 + q))*Dn + h*DVn + d] = r;
  }
}

// ---------------- Wo projection into Xc ----------------
__global__ void wo_xc_tiled(const float2* __restrict__ Ob, const float2* __restrict__ wos,
                            float2* __restrict__ Xc, int m0, size_t mstride){
  int ml = blockIdx.y;
  int m = m0 + ml;
  const float2* O = Ob + (size_t)ml*mstride;
  const float2* Wo_ = wos + (size_t)m*Dn*Dn;
  int seg = m;
  int bx = blockIdx.x;
  int lt = bx & 3, dt = (bx >> 2) & 7, b = bx >> 5;
  int l0 = lt*64, d0 = dt*32;
  __shared__ float2 Os[16][65];
  __shared__ float2 Ws[16][32];
  int tid = threadIdx.x;
  int tx = tid & 15, ty = tid >> 4;
  float2 acc[2][4];
  #pragma unroll
  for (int k = 0; k < 2; ++k)
    #pragma unroll
    for (int j = 0; j < 4; ++j) acc[k][j] = make_float2(0.f, 0.f);
  for (int e0 = 0; e0 < Dn; e0 += 16){
    for (int j = tid; j < 16*64; j += 256){
      int ll = j >> 4, ee = j & 15;
      Os[ee][ll] = O[((size_t)(b*Ln + l0 + ll))*Dn + e0 + ee];
    }
    for (int j = tid; j < 16*32; j += 256){
      int ee = j >> 5, dd = j & 31;
      Ws[ee][dd] = Wo_[(size_t)(e0 + ee)*Dn + d0 + dd];
    }
    __syncthreads();
    #pragma unroll
    for (int ee = 0; ee < 16; ++ee){
      float2 a[4], w[2];
      #pragma unroll
      for (int j = 0; j < 4; ++j) a[j] = Os[ee][tx + j*16];
      #pragma unroll
      for (int k = 0; k < 2; ++k) w[k] = Ws[ee][ty*2 + k];
      #pragma unroll
      for (int k = 0; k < 2; ++k)
        #pragma unroll
        for (int j = 0; j < 4; ++j) acc[k][j] = cfma(a[j], w[k], acc[k][j]);
    }
    __syncthreads();
  }
  #pragma unroll
  for (int k = 0; k < 2; ++k)
    #pragma unroll
    for (int j = 0; j < 4; ++j)
      Xc[((size_t)(b*Dn + d0 + ty*2 + k))*L4n + seg*Ln + l0 + tx + j*16] = acc[k][j];
}

// mean over last dim (1024), one block per row
__global__ void row_mean_kernel(const float2* __restrict__ X, float2* __restrict__ y){
  int row = blockIdx.x;
  int tid = threadIdx.x;
  float sx = 0.f, sy = 0.f;
  const float2* xr = X + (size_t)row*L4n;
  for (int i = tid; i < L4n; i += 256){ float2 v = xr[i]; sx += v.x; sy += v.y; }
  __shared__ float rx[256], ry[256];
  rx[tid] = sx; ry[tid] = sy; __syncthreads();
  for (int st = 128; st > 0; st >>= 1){
    if (tid < st){ rx[tid] += rx[tid+st]; ry[tid] += ry[tid+st]; }
    __syncthreads();
  }
  if (tid == 0) y[row] = make_float2(rx[0]*(1.f/L4n), ry[0]*(1.f/L4n));
}

__global__ void eca_gate_kernel(const float2* __restrict__ y, const float2* __restrict__ w,
                                float2* __restrict__ g, int C){
  int idx = blockIdx.x*blockDim.x + threadIdx.x;
  if (idx >= Bn*C) return;
  int c = idx % C;
  int b = idx / C;
  float2 z = make_float2(0.f, 0.f);
  #pragma unroll
  for (int i = 0; i < KEn; ++i){
    int cc = c + i - 2;
    if (cc >= 0 && cc < C) z = cfma(w[i], y[b*C + cc], z);
  }
  g[idx] = make_float2(1.f/(1.f + expf(-z.x)), 1.f/(1.f + expf(-z.y)));
}

__global__ void eca_apply_kernel(float2* __restrict__ X, const float2* __restrict__ g){
  int idx = blockIdx.x*256 + threadIdx.x;
  int row = idx >> 10;
  X[idx] = cmul(X[idx], g[row]);
}

// ---------------- D x D x 3 conv over length 1024 ----------------
__global__ void conv_dd_tiled(const float2* __restrict__ X, const float2* __restrict__ W,
                              float2* __restrict__ out, int ochans){
  __shared__ float2 Xs[16][66];
  __shared__ float2 Ws[32][49];
  int bx = blockIdx.x;
  int xt = bx & 15, ot = (bx >> 4) & 7, b = bx >> 7;
  int x0 = xt*64, o0 = ot*32;
  int tid = threadIdx.x;
  int tx = tid & 15, ty = tid >> 4;
  float2 acc[2][4];
  #pragma unroll
  for (int k = 0; k < 2; ++k)
    #pragma unroll
    for (int j = 0; j < 4; ++j) acc[k][j] = make_float2(0.f, 0.f);
  const float2* xb = X + (size_t)b*Dn*L4n;
  for (int c0 = 0; c0 < Dn; c0 += 16){
    for (int j = tid; j < 16*66; j += 256){
      int cc = j / 66, xx = j - cc*66;
      int gx = x0 + xx - 1;
      float2 v = make_float2(0.f, 0.f);
      if (gx >= 0 && gx < L4n) v = xb[(size_t)(c0 + cc)*L4n + gx];
      Xs[cc][xx] = v;
    }
    for (int j = tid; j < 32*48; j += 256){
      int o = j / 48, r = j - o*48;
      Ws[o][r] = W[(size_t)(o0 + o)*Dn*KWn + c0*KWn + r];
    }
    __syncthreads();
    #pragma unroll
    for (int cc = 0; cc < 16; ++cc){
      float2 xv[4][3];
      #pragma unroll
      for (int j = 0; j < 4; ++j)
        #pragma unroll
        for (int i = 0; i < 3; ++i) xv[j][i] = Xs[cc][tx + j*16 + i];
      #pragma unroll
      for (int k = 0; k < 2; ++k){
        float2 w0 = Ws[ty*2 + k][cc*3 + 0];
        float2 w1 = Ws[ty*2 + k][cc*3 + 1];
        float2 w2 = Ws[ty*2 + k][cc*3 + 2];
        #pragma unroll
        for (int j = 0; j < 4; ++j){
          acc[k][j] = cfma(xv[j][0], w0, acc[k][j]);
          acc[k][j] = cfma(xv[j][1], w1, acc[k][j]);
          acc[k][j] = cfma(xv[j][2], w2, acc[k][j]);
        }
      }
    }
    __syncthreads();
  }
  #pragma unroll
  for (int k = 0; k < 2; ++k)
    #pragma unroll
    for (int j = 0; j < 4; ++j)
      out[((size_t)(b*ochans + o0 + ty*2 + k))*L4n + x0 + tx + j*16] = acc[k][j];
}

} // namespace

extern "C" void kernel_launch(void* const* d_in, const int* in_sizes, int n_in,
                              void* d_out, int out_size, void* d_ws, size_t ws_size,
                              hipStream_t stream){
  const float2* X1 = (const float2*)d_in[0];
  const float2* X2 = (const float2*)d_in[1];
  const float2* head_w = (const float2*)d_in[2];
  const float2* head_b = (const float2*)d_in[3];
  const float2* wq = (const float2*)d_in[4];
  const float2* wk = (const float2*)d_in[5];
  const float2* wv = (const float2*)d_in[6];
  const float2* wo = (const float2*)d_in[7];
  const float2* se = (const float2*)d_in[8];
  const float2* sc = (const float2*)d_in[9];
  const float2* te = (const float2*)d_in[10];

  const size_t SZ_BDL = (size_t)Bn*Dn*Ln;      // 524288 complex = 4 MB
  const size_t SZ_X   = (size_t)Bn*Dn*L4n;     // 16 MB
  const size_t small  = 2*(size_t)Bn*2*Dn;

  int mcount = 1;
  {
    size_t need4 = ((size_t)4 + 16)*SZ_BDL + SZ_X + small;
    size_t need2 = ((size_t)4 + 8)*SZ_BDL + SZ_X + small;
    if (ws_size >= need4*sizeof(float2)) mcount = 4;
    else if (ws_size >= need2*sizeof(float2)) mcount = 2;
  }

  float2* p = (float2*)d_ws;
  float2* A  = p;  p += SZ_BDL;
  float2* Bc = p;  p += SZ_BDL;
  float2* iA = p;  p += SZ_BDL;
  float2* iB = p;  p += SZ_BDL;
  float2* Qb = p;  p += (size_t)mcount*SZ_BDL;
  float2* Kb = p;  p += (size_t)mcount*SZ_BDL;
  float2* Vb = p;  p += (size_t)mcount*SZ_BDL;
  float2* Ob = p;  p += (size_t)mcount*SZ_BDL;
  float2* Xc = p;  p += SZ_X;
  float2* ybuf = p; p += (size_t)Bn*2*Dn;
  float2* gbuf = p; p += (size_t)Bn*2*Dn;

  float2* out0 = (float2*)d_out;                   // [B, 512, 1024]
  float2* out1 = out0 + (size_t)Bn*2*Dn*L4n;

  head_conv_kernel<<<(Bn*Dn*Ln)/256, 256, 0, stream>>>(X1, head_w, head_b, A);
  head_conv_kernel<<<(Bn*Dn*Ln)/256, 256, 0, stream>>>(
      X2, head_w + (size_t)Dn*CINn*KWn, head_b + Dn, Bc);

  fft_rows_kernel<256,8><<<Bn*Dn, 256, 0, stream>>>(A,  iA, 256,0,256,0, 1.0f, 1.0f/256.0f);
  fft_rows_kernel<256,8><<<Bn*Dn, 256, 0, stream>>>(Bc, iB, 256,0,256,0, 1.0f, 1.0f/256.0f);

  auto run_ssca = [&](const float2* Ap, const float2* Bp, int set, float2* dstbase){
    const float2* wq_s = wq + (size_t)set*4*Dn*Dn;
    const float2* wk_s = wk + (size_t)set*4*Dn*Dn;
    const float2* wv_s = wv + (size_t)set*4*Dn*Dn;
    const float2* wo_s = wo + (size_t)set*4*Dn*Dn;
    for (int m0 = 0; m0 < 4; m0 += mcount){
      qkv_proj_kernel<<<dim3(Bn*16, 3*mcount), 256, 0, stream>>>(
          Ap, Bp, wq_s, wk_s, wv_s, Qb, Kb, Vb, m0, SZ_BDL);
      attn_fused_kernel<<<dim3(Bn*Hn*16, mcount), 256, 0, stream>>>(Qb, Kb, Vb, Ob, SZ_BDL);
      wo_xc_tiled<<<dim3(Bn*32, mcount), 256, 0, stream>>>(Ob, wo_s, Xc, m0, SZ_BDL);
    }
    row_mean_kernel<<<Bn*Dn, 256, 0, stream>>>(Xc, ybuf);
    eca_gate_kernel<<<(Bn*Dn + 255)/256, 256, 0, stream>>>(ybuf, se + set*KEn, gbuf, Dn);
    eca_apply_kernel<<<(int)(SZ_X/256), 256, 0, stream>>>(Xc, gbuf);
    conv_dd_tiled<<<Bn*128, 256, 0, stream>>>(Xc, sc + (size_t)set*Dn*Dn*KWn, dstbase, 2*Dn);
  };

  run_ssca(A,  Bc, 0, out0);   // R  -> out0 channels [0,256)
  run_ssca(iA, iB, 1, out1);   // kk -> out1 channels [0,256)

  // R2[:,256:] = fft(kk) ; k2[:,256:] = ifft(R)
  fft_rows_kernel<1024,10><<<Bn*Dn, 256, 0, stream>>>(out1, out0, 2*Dn,0, 2*Dn,Dn, -1.0f, 1.0f);
  fft_rows_kernel<1024,10><<<Bn*Dn, 256, 0, stream>>>(out0, out1, 2*Dn,0, 2*Dn,Dn, 1.0f, 1.0f/1024.0f);

  for (int t = 0; t < 2; ++t){
    float2* op = (t == 0) ? out0 : out1;
    row_mean_kernel<<<Bn*2*Dn, 256, 0, stream>>>(op, ybuf);
    eca_gate_kernel<<<(Bn*2*Dn + 255)/256, 256, 0, stream>>>(ybuf, te + t*KEn, gbuf, 2*Dn);
    eca_apply_kernel<<<(Bn*2*Dn*L4n)/256, 256, 0, stream>>>(op, gbuf);
  }
}

// Round 6
// 670.522 us; speedup vs baseline: 6.8157x; 1.9169x over previous
//
#include <hip/hip_runtime.h>
#include <math.h>

namespace {

constexpr int Bn = 8, CINn = 16, Ln = 256, Dn = 256, Hn = 8, DKn = 32, DVn = 32;
constexpr int KWn = 3, KEn = 5, L4n = 1024;
constexpr float EPSf = 1e-9f;
constexpr int XP = 1040;   // bf16 X-plane pitch (8-col halo each side)
constexpr int LP = 40;     // LDS pitch in ushorts for 32-k chunk (80B: 16B-aligned, ~2-way banks)

typedef __attribute__((ext_vector_type(8))) short short8b;
typedef __attribute__((ext_vector_type(4))) float f32x4;

__device__ __forceinline__ float2 cmul(float2 a, float2 b){
  return make_float2(a.x*b.x - a.y*b.y, a.x*b.y + a.y*b.x);
}
__device__ __forceinline__ float2 cfma(float2 a, float2 b, float2 c){
  c.x = fmaf(a.x, b.x, c.x); c.x = fmaf(-a.y, b.y, c.x);
  c.y = fmaf(a.x, b.y, c.y); c.y = fmaf(a.y, b.x, c.y);
  return c;
}
__device__ __forceinline__ ushort f2bf(float f){
  uint u = __float_as_uint(f);
  u += 0x7fffu + ((u >> 16) & 1u);   // RNE
  return (ushort)(u >> 16);
}
__device__ __forceinline__ short8b neg8(short8b v){
  union { short8b s; uint u[4]; } x; x.s = v;
  #pragma unroll
  for (int i = 0; i < 4; ++i) x.u[i] ^= 0x80008000u;
  return x.s;
}

// A[b,o,l] = sum_c sum_i X[b,c,l+i-1] * hw[o,c,i] + hb[o]
__global__ void head_conv_kernel(const float2* __restrict__ X, const float2* __restrict__ hw,
                                 const float2* __restrict__ hb, float2* __restrict__ out){
  int idx = blockIdx.x * blockDim.x + threadIdx.x;
  if (idx >= Bn*Dn*Ln) return;
  int l = idx & (Ln-1);
  int o = (idx >> 8) & (Dn-1);
  int b = idx >> 16;
  float2 acc = hb[o];
  for (int c = 0; c < CINn; ++c){
    const float2* xr = X + (size_t)(b*CINn + c)*Ln;
    const float2* wr = hw + (size_t)(o*CINn + c)*KWn;
    #pragma unroll
    for (int i = 0; i < KWn; ++i){
      int ll = l + i - 1;
      if (ll >= 0 && ll < Ln) acc = cfma(xr[ll], wr[i], acc);
    }
  }
  out[idx] = acc;
}

// In-LDS radix-2 FFT with twiddle table; rows mapped through (chans, coff).
template<int N, int LOG>
__global__ void fft_rows_kernel(const float2* __restrict__ src0, float2* __restrict__ dst0,
                                int schans, int scoff, int dchans, int dcoff,
                                float sign, float scale){
  __shared__ float2 buf[N];
  __shared__ float2 tw[N/2];
  int row = blockIdx.x;
  int rb = row >> 8, rc = row & 255;
  const float2* src = src0 + (size_t)(rb*schans + scoff + rc)*N;
  float2* dst = dst0 + (size_t)(rb*dchans + dcoff + rc)*N;
  int tid = threadIdx.x;
  for (int i = tid; i < N/2; i += 256){
    float a = sign * 6.2831853071795864f * (float)i / (float)N;
    float s, c; __sincosf(a, &s, &c);
    tw[i] = make_float2(c, s);
  }
  for (int i = tid; i < N; i += 256){
    unsigned r = __brev((unsigned)i) >> (32 - LOG);
    buf[r] = src[i];
  }
  __syncthreads();
  for (int st = 1; st <= LOG; ++st){
    int half = 1 << (st-1);
    for (int bf = tid; bf < N/2; bf += 256){
      int blk = bf >> (st-1);
      int pos = bf & (half-1);
      int i0 = (blk << st) + pos;
      int i1 = i0 + half;
      float2 w = tw[pos << (LOG-st)];
      float2 u = buf[i0];
      float2 t = cmul(w, buf[i1]);
      buf[i0] = make_float2(u.x + t.x, u.y + t.y);
      buf[i1] = make_float2(u.x - t.x, u.y - t.y);
    }
    __syncthreads();
  }
  for (int i = tid; i < N; i += 256)
    dst[i] = make_float2(buf[i].x * scale, buf[i].y * scale);
}

// ---------------- unified complex bf16 MFMA GEMM core ----------------
// C[m,n] = sum_k A[m,k]*B[k,n] (complex), A/B as bf16 re/im planes.
// Block tile 64m x 64n, K-chunk 32, 4 waves (2x2 of 32x32 wave tiles).
// conv!=0: B row k -> Xplane row c=k/3, col 8+n0+nn+(k%3)-1 (halo layout).
// cmode 0: cbase[m*crow + n]; cmode 1: cbase[n*crow + m] via LDS transpose (coalesced).
__device__ __forceinline__ void cgemm_core(
    const ushort* __restrict__ Are, const ushort* __restrict__ Aim, int pitchA, int am0,
    const ushort* __restrict__ Bre, const ushort* __restrict__ Bim, int pitchB, int n0,
    int K, int conv, float2* __restrict__ cbase, size_t crow, int cmode)
{
  __shared__ ushort sh[10240];           // A re|im (2x2560) + B re|im (2x2560); T overlay
  ushort* As_re = sh;
  ushort* As_im = sh + 2560;
  ushort* Bs_re = sh + 5120;
  ushort* Bs_im = sh + 7680;
  int tid = threadIdx.x;
  int lane = tid & 63, w = tid >> 6;
  int wm = w >> 1, wn = w & 1;
  int lrow = lane & 15, lhalf = lane >> 4;
  f32x4 ar[2][2], ai[2][2];
  #pragma unroll
  for (int s = 0; s < 2; ++s)
    #pragma unroll
    for (int t = 0; t < 2; ++t){ ar[s][t] = (f32x4){0,0,0,0}; ai[s][t] = (f32x4){0,0,0,0}; }
  int nk = K >> 5;
  for (int kc = 0; kc < nk; ++kc){
    int k0 = kc << 5;
    __syncthreads();
    // stage A: 64 rows x 32 k, 8B vector loads
    #pragma unroll
    for (int rep = 0; rep < 2; ++rep){
      int q = tid + rep*256;
      int row = q >> 3, kq = (q & 7)*4;
      size_t go = (size_t)(am0 + row)*pitchA + k0 + kq;
      *(uint2*)&As_re[row*LP + kq] = *(const uint2*)&Are[go];
      *(uint2*)&As_im[row*LP + kq] = *(const uint2*)&Aim[go];
    }
    if (!conv){
      // stage B transposed: LDS [n][k]
      #pragma unroll
      for (int rep = 0; rep < 2; ++rep){
        int q = tid + rep*256;
        int k = q >> 4, nq = (q & 15)*4;
        size_t go = (size_t)(k0 + k)*pitchB + n0 + nq;
        uint2 vr = *(const uint2*)&Bre[go];
        uint2 vi = *(const uint2*)&Bim[go];
        ushort* dr = &Bs_re[nq*LP + k];
        ushort* di = &Bs_im[nq*LP + k];
        dr[0]    = (ushort)(vr.x);      di[0]    = (ushort)(vi.x);
        dr[LP]   = (ushort)(vr.x>>16);  di[LP]   = (ushort)(vi.x>>16);
        dr[2*LP] = (ushort)(vr.y);      di[2*LP] = (ushort)(vi.y);
        dr[3*LP] = (ushort)(vr.y>>16);  di[3*LP] = (ushort)(vi.y>>16);
      }
    } else {
      #pragma unroll
      for (int rep = 0; rep < 8; ++rep){
        int idx = tid + rep*256;
        int k = idx >> 6, nn = idx & 63;
        uint kk = (uint)(k0 + k);
        uint c = (kk * 0xAAABu) >> 17;      // kk/3
        int i = (int)(kk - c*3u);
        size_t go = (size_t)c*XP + 8 + n0 + nn + i - 1;
        Bs_re[nn*LP + k] = Bre[go];
        Bs_im[nn*LP + k] = Bim[go];
      }
    }
    __syncthreads();
    short8b afr[2], afi[2], bfr[2], bfi[2];
    #pragma unroll
    for (int s = 0; s < 2; ++s){
      int row = wm*32 + s*16 + lrow;
      afr[s] = *(const short8b*)&As_re[row*LP + lhalf*8];
      afi[s] = *(const short8b*)&As_im[row*LP + lhalf*8];
    }
    #pragma unroll
    for (int t = 0; t < 2; ++t){
      int row = wn*32 + t*16 + lrow;
      bfr[t] = *(const short8b*)&Bs_re[row*LP + lhalf*8];
      bfi[t] = *(const short8b*)&Bs_im[row*LP + lhalf*8];
    }
    #pragma unroll
    for (int s = 0; s < 2; ++s){
      short8b ain = neg8(afi[s]);
      #pragma unroll
      for (int t = 0; t < 2; ++t){
        ar[s][t] = __builtin_amdgcn_mfma_f32_16x16x32_bf16(ain,    bfi[t], ar[s][t], 0, 0, 0);
        ar[s][t] = __builtin_amdgcn_mfma_f32_16x16x32_bf16(afr[s], bfr[t], ar[s][t], 0, 0, 0);
        ai[s][t] = __builtin_amdgcn_mfma_f32_16x16x32_bf16(afi[s], bfr[t], ai[s][t], 0, 0, 0);
        ai[s][t] = __builtin_amdgcn_mfma_f32_16x16x32_bf16(afr[s], bfi[t], ai[s][t], 0, 0, 0);
      }
    }
  }
  if (cmode == 0){
    #pragma unroll
    for (int s = 0; s < 2; ++s)
      #pragma unroll
      for (int t = 0; t < 2; ++t)
        #pragma unroll
        for (int r = 0; r < 4; ++r){
          int mm = wm*32 + s*16 + lhalf*4 + r;
          int nn = wn*32 + t*16 + lrow;
          cbase[(size_t)mm*crow + nn] = make_float2(ar[s][t][r], ai[s][t][r]);
        }
  } else {
    float2* T = (float2*)sh;               // [64][33] float2, 16.9KB
    #pragma unroll
    for (int h = 0; h < 2; ++h){
      __syncthreads();
      if (wn == h){
        #pragma unroll
        for (int s = 0; s < 2; ++s)
          #pragma unroll
          for (int t = 0; t < 2; ++t)
            #pragma unroll
            for (int r = 0; r < 4; ++r){
              int mm = wm*32 + s*16 + lhalf*4 + r;
              int nn = t*16 + lrow;
              T[mm*33 + nn] = make_float2(ar[s][t][r], ai[s][t][r]);
            }
      }
      __syncthreads();
      #pragma unroll
      for (int rep = 0; rep < 8; ++rep){
        int idx = tid + rep*256;
        int mm = idx & 63, nn = idx >> 6;  // nn 0..31
        cbase[(size_t)(h*32 + nn)*crow + mm] = T[mm*33 + nn];
      }
    }
  }
}

// ---------------- GEMM wrappers ----------------
__global__ __launch_bounds__(256) void qkv_mfma(
    const ushort* __restrict__ aAre, const ushort* __restrict__ aAim,
    const ushort* __restrict__ aBre, const ushort* __restrict__ aBim,
    const ushort* __restrict__ WqRe, const ushort* __restrict__ WqIm,
    const ushort* __restrict__ WkRe, const ushort* __restrict__ WkIm,
    const ushort* __restrict__ WvRe, const ushort* __restrict__ WvIm,
    float2* __restrict__ Qb, float2* __restrict__ Kb, float2* __restrict__ Vb,
    int set, int m0, size_t mstride)
{
  int my = blockIdx.y;
  int ml = my / 3, which = my - ml*3;
  int m = m0 + ml;
  bool useA = (which == 0) ? (m == 0 || m == 2) : (m == 0 || m == 3);
  const ushort* Are = useA ? aAre : aBre;
  const ushort* Aim = useA ? aAim : aBim;
  const ushort* WRe = (which == 0) ? WqRe : (which == 1) ? WkRe : WvRe;
  const ushort* WIm = (which == 0) ? WqIm : (which == 1) ? WkIm : WvIm;
  size_t woff = (size_t)(set*4 + m)*Dn*Dn;
  int bx = blockIdx.x;
  int nt = bx & 3, mt = (bx >> 2) & 3, b = bx >> 4;
  int l0 = mt*64, e0 = nt*64;
  const ushort* ARe = Are + (size_t)b*Ln*Dn;
  const ushort* AIm = Aim + (size_t)b*Ln*Dn;
  if (which == 1){
    float2* cb = Kb + (size_t)ml*mstride + ((size_t)b*Dn + e0)*Ln + l0;
    cgemm_core(ARe, AIm, Dn, l0, WRe + woff, WIm + woff, Dn, e0, Dn, 0, cb, Ln, 1);
  } else {
    float2* out = ((which == 0) ? Qb : Vb) + (size_t)ml*mstride;
    float2* cb = out + ((size_t)b*Ln + l0)*Dn + e0;
    cgemm_core(ARe, AIm, Dn, l0, WRe + woff, WIm + woff, Dn, e0, Dn, 0, cb, Dn, 0);
  }
}

__global__ __launch_bounds__(256) void wo_mfma(
    const ushort* __restrict__ ORe, const ushort* __restrict__ OIm,
    const ushort* __restrict__ WoRe, const ushort* __restrict__ WoIm,
    float2* __restrict__ Xc, int set, int m0)
{
  int ml = blockIdx.y;
  int m = m0 + ml;
  size_t woff = (size_t)(set*4 + m)*Dn*Dn;
  int bx = blockIdx.x;
  int nt = bx & 3, mt = (bx >> 2) & 3, b = bx >> 4;
  int l0 = mt*64, d0 = nt*64;
  const ushort* ARe = ORe + ((size_t)ml*Bn + b)*Ln*Dn;
  const ushort* AIm = OIm + ((size_t)ml*Bn + b)*Ln*Dn;
  float2* cb = Xc + ((size_t)b*Dn + d0)*L4n + m*Ln + l0;
  cgemm_core(ARe, AIm, Dn, l0, WoRe + woff, WoIm + woff, Dn, d0, Dn, 0, cb, L4n, 1);
}

__global__ __launch_bounds__(256) void conv_mfma(
    const ushort* __restrict__ WRe, const ushort* __restrict__ WIm,
    const ushort* __restrict__ XRe, const ushort* __restrict__ XIm,
    float2* __restrict__ out, int ochans)
{
  int bx = blockIdx.x;
  int xt = bx & 15, ot = (bx >> 4) & 3, b = bx >> 6;
  int o0 = ot*64, x0 = xt*64;
  const ushort* xr = XRe + (size_t)b*Dn*XP;
  const ushort* xi = XIm + (size_t)b*Dn*XP;
  float2* cb = out + ((size_t)(b*ochans) + o0)*L4n + x0;
  cgemm_core(WRe, WIm, 768, o0, xr, xi, XP, x0, 768, 1, cb, L4n, 0);
}

// ---------------- pack kernels ----------------
// [B,D,L] complex f32 -> transposed bf16 planes [B][L][D]
__global__ void pack_at(const float2* __restrict__ in, ushort* __restrict__ ore,
                        ushort* __restrict__ oim){
  __shared__ float2 T[32][33];
  int bx = blockIdx.x;
  int lt = bx & 7, dt = (bx >> 3) & 7, b = bx >> 6;
  int tid = threadIdx.x;
  int c = tid & 31, rr = tid >> 5;
  #pragma unroll
  for (int it = 0; it < 4; ++it){
    int d = rr + it*8;
    T[d][c] = in[((size_t)b*Dn + dt*32 + d)*Ln + lt*32 + c];
  }
  __syncthreads();
  #pragma unroll
  for (int it = 0; it < 4; ++it){
    int l = rr + it*8;
    float2 v = T[c][l];
    size_t o = ((size_t)b*Ln + lt*32 + l)*Dn + dt*32 + c;
    ore[o] = f2bf(v.x); oim[o] = f2bf(v.y);
  }
}

__global__ void pack_w(const float2* __restrict__ wq, const float2* __restrict__ wk,
                       const float2* __restrict__ wv, const float2* __restrict__ wo,
                       ushort* r0, ushort* i0, ushort* r1, ushort* i1,
                       ushort* r2, ushort* i2, ushort* r3, ushort* i3){
  int f = blockIdx.y;
  const float2* in = (f == 0) ? wq : (f == 1) ? wk : (f == 2) ? wv : wo;
  ushort* orr = (f == 0) ? r0 : (f == 1) ? r1 : (f == 2) ? r2 : r3;
  ushort* oii = (f == 0) ? i0 : (f == 1) ? i1 : (f == 2) ? i2 : i3;
  size_t idx = (size_t)blockIdx.x*256 + threadIdx.x;
  float2 v = in[idx];
  orr[idx] = f2bf(v.x); oii[idx] = f2bf(v.y);
}

__global__ void pack_sc(const float2* __restrict__ sc, ushort* __restrict__ ore,
                        ushort* __restrict__ oim){
  size_t idx = (size_t)blockIdx.x*256 + threadIdx.x;   // < 2*256*768
  float2 v = sc[idx];
  ore[idx] = f2bf(v.x); oim[idx] = f2bf(v.y);
}

// X *= gate, write bf16 planes with halo pads (Xc fp32 not written back)
__global__ void eca_apply_pack(const float2* __restrict__ X, const float2* __restrict__ g,
                               ushort* __restrict__ xre, ushort* __restrict__ xim){
  int idx = blockIdx.x*256 + threadIdx.x;
  int row = idx >> 10, x = idx & 1023;
  float2 v = cmul(X[idx], g[row]);
  size_t o = (size_t)row*XP + 8 + x;
  xre[o] = f2bf(v.x); xim[o] = f2bf(v.y);
  if (x < 8){ size_t o2 = (size_t)row*XP + x; xre[o2] = 0; xim[o2] = 0; }
  if (x >= 1016){ size_t o2 = (size_t)row*XP + x + 16; xre[o2] = 0; xim[o2] = 0; }
}

// ---------------- fused attention (fp32 core), writes bf16 O planes ----------------
__global__ void attn_fused_kernel(const float2* __restrict__ Qb, const float2* __restrict__ KTb,
                                  const float2* __restrict__ Vb,
                                  ushort* __restrict__ ORe, ushort* __restrict__ OIm,
                                  size_t mstride, size_t ostr){
  const float2* Q  = Qb  + (size_t)blockIdx.y*mstride;
  const float2* KT = KTb + (size_t)blockIdx.y*mstride;
  const float2* V  = Vb  + (size_t)blockIdx.y*mstride;
  ushort* Ore_ = ORe + (size_t)blockIdx.y*ostr;
  ushort* Oim_ = OIm + (size_t)blockIdx.y*ostr;
  int bx = blockIdx.x;
  int qt = bx & 15, h = (bx >> 4) & 7, b = bx >> 7;
  int q0 = qt*16;
  int tid = threadIdx.x;
  __shared__ float2 smem[528 + 4112];   // Qs[16][33] | Ps[16][257]
  float2* Qs = smem;
  float2* Ps = smem + 528;
  const float scl = 0.17677669529663687f;
  for (int j = tid; j < 16*32; j += 256){
    int r = j >> 5, c = j & 31;
    float2 v = Q[((size_t)(b*Ln + q0 + r))*Dn + h*DKn + c];
    Qs[r*33 + c] = make_float2(v.x*scl, v.y*scl);
  }
  __syncthreads();
  float2 acc[16];
  #pragma unroll
  for (int q = 0; q < 16; ++q) acc[q] = make_float2(0.f, 0.f);
  const float2* ktbase = KT + ((size_t)(b*Dn + h*DKn))*Ln + tid;
  #pragma unroll
  for (int dc = 0; dc < 4; ++dc){
    float2 kreg[8];
    #pragma unroll
    for (int dd = 0; dd < 8; ++dd)
      kreg[dd] = ktbase[(size_t)(dc*8 + dd)*Ln];
    #pragma unroll
    for (int dd = 0; dd < 8; ++dd)
      #pragma unroll
      for (int q = 0; q < 16; ++q)
        acc[q] = cfma(Qs[q*33 + dc*8 + dd], kreg[dd], acc[q]);
  }
  #pragma unroll
  for (int q = 0; q < 16; ++q) Ps[q*257 + tid] = acc[q];
  __syncthreads();
  {
    int q = tid >> 4, g = tid & 15;
    float mn = 3.4e38f, mx = 0.f;
    #pragma unroll
    for (int t = 0; t < 16; ++t){
      float2 s = Ps[q*257 + g + t*16];
      float m = sqrtf(s.x*s.x + s.y*s.y);
      mn = fminf(mn, m); mx = fmaxf(mx, m);
    }
    #pragma unroll
    for (int off = 1; off < 16; off <<= 1){
      mn = fminf(mn, __shfl_xor(mn, off));
      mx = fmaxf(mx, __shfl_xor(mx, off));
    }
    if (g == 0) Qs[q*33 + 32] = make_float2(mn, mx);
  }
  __syncthreads();
  #pragma unroll
  for (int q = 0; q < 16; ++q){
    float2 mm = Qs[q*33 + 32];
    float mag = sqrtf(acc[q].x*acc[q].x + acc[q].y*acc[q].y);
    float f = ((mag - mm.x) / (mm.y - mm.x + EPSf)) / (mag + EPSf);
    Ps[q*257 + tid] = make_float2(acc[q].x*f, acc[q].y*f);
  }
  __syncthreads();
  int kc = tid >> 5, dv = tid & 31;
  float2 oacc[16];
  #pragma unroll
  for (int q = 0; q < 16; ++q) oacc[q] = make_float2(0.f, 0.f);
  const float2* vbase = V + ((size_t)(b*Ln + kc*32))*Dn + h*DVn + dv;
  #pragma unroll 4
  for (int kk = 0; kk < 32; ++kk){
    float2 vv = vbase[(size_t)kk*Dn];
    int k = kc*32 + kk;
    #pragma unroll
    for (int q = 0; q < 16; ++q)
      oacc[q] = cfma(Ps[q*257 + k], vv, oacc[q]);
  }
  __syncthreads();
  float2* buf = Ps;                      // [4][16][32]
  #pragma unroll
  for (int q = 0; q < 16; ++q){
    oacc[q].x += __shfl_xor(oacc[q].x, 32);
    oacc[q].y += __shfl_xor(oacc[q].y, 32);
  }
  int wv = tid >> 6, lane = tid & 63;
  if (lane < 32){
    #pragma unroll
    for (int q = 0; q < 16; ++q)
      buf[wv*512 + q*32 + dv] = oacc[q];
  }
  __syncthreads();
  #pragma unroll
  for (int half = 0; half < 2; ++half){
    int o = tid + half*256;
    int q = o >> 5, d = o & 31;
    float2 r = buf[o];
    #pragma unroll
    for (int w = 1; w < 4; ++w){
      float2 t = buf[w*512 + o];
      r.x += t.x; r.y += t.y;
    }
    size_t oo = ((size_t)(b*Ln + q0 + q))*Dn + h*DVn + d;
    Ore_[oo] = f2bf(r.x); Oim_[oo] = f2bf(r.y);
  }
}

// mean over last dim (1024), one block per row
__global__ void row_mean_kernel(const float2* __restrict__ X, float2* __restrict__ y){
  int row = blockIdx.x;
  int tid = threadIdx.x;
  float sx = 0.f, sy = 0.f;
  const float2* xr = X + (size_t)row*L4n;
  for (int i = tid; i < L4n; i += 256){ float2 v = xr[i]; sx += v.x; sy += v.y; }
  __shared__ float rx[256], ry[256];
  rx[tid] = sx; ry[tid] = sy; __syncthreads();
  for (int st = 128; st > 0; st >>= 1){
    if (tid < st){ rx[tid] += rx[tid+st]; ry[tid] += ry[tid+st]; }
    __syncthreads();
  }
  if (tid == 0) y[row] = make_float2(rx[0]*(1.f/L4n), ry[0]*(1.f/L4n));
}

__global__ void eca_gate_kernel(const float2* __restrict__ y, const float2* __restrict__ w,
                                float2* __restrict__ g, int C){
  int idx = blockIdx.x*blockDim.x + threadIdx.x;
  if (idx >= Bn*C) return;
  int c = idx % C;
  int b = idx / C;
  float2 z = make_float2(0.f, 0.f);
  #pragma unroll
  for (int i = 0; i < KEn; ++i){
    int cc = c + i - 2;
    if (cc >= 0 && cc < C) z = cfma(w[i], y[b*C + cc], z);
  }
  g[idx] = make_float2(1.f/(1.f + expf(-z.x)), 1.f/(1.f + expf(-z.y)));
}

__global__ void eca_apply_kernel(float2* __restrict__ X, const float2* __restrict__ g){
  int idx = blockIdx.x*256 + threadIdx.x;
  int row = idx >> 10;
  X[idx] = cmul(X[idx], g[row]);
}

} // namespace

extern "C" void kernel_launch(void* const* d_in, const int* in_sizes, int n_in,
                              void* d_out, int out_size, void* d_ws, size_t ws_size,
                              hipStream_t stream){
  const float2* X1 = (const float2*)d_in[0];
  const float2* X2 = (const float2*)d_in[1];
  const float2* head_w = (const float2*)d_in[2];
  const float2* head_b = (const float2*)d_in[3];
  const float2* wq = (const float2*)d_in[4];
  const float2* wk = (const float2*)d_in[5];
  const float2* wv = (const float2*)d_in[6];
  const float2* wo = (const float2*)d_in[7];
  const float2* se = (const float2*)d_in[8];
  const float2* sc = (const float2*)d_in[9];
  const float2* te = (const float2*)d_in[10];

  const size_t SZ_BDL = (size_t)Bn*Dn*Ln;      // 524288 complex = 4 MB
  const size_t SZ_X   = (size_t)Bn*Dn*L4n;     // 16 MB
  const size_t small  = 2*(size_t)Bn*2*Dn;
  const size_t NAt    = (size_t)Bn*Ln*Dn;      // ushorts per plane (A-side)

  // ushort plane budget (excl. O planes which scale with mcount)
  const size_t US_FIX = 2*(4*NAt)               // At planes (4 inputs)
                      + 2*(4*8*(size_t)65536)   // wq/wk/wv/wo planes
                      + 2*(2*(size_t)Dn*768)    // sc planes
                      + 2*((size_t)Bn*Dn*XP);   // X planes
  auto need_bytes = [&](int mc){
    return ((4 + (size_t)3*mc)*SZ_BDL + SZ_X + small)*sizeof(float2)
         + (US_FIX + 2*(size_t)mc*NAt)*sizeof(ushort);
  };
  int mcount = 1;
  if (ws_size >= need_bytes(4)) mcount = 4;
  else if (ws_size >= need_bytes(2)) mcount = 2;

  float2* p = (float2*)d_ws;
  float2* A  = p;  p += SZ_BDL;
  float2* Bc = p;  p += SZ_BDL;
  float2* iA = p;  p += SZ_BDL;
  float2* iB = p;  p += SZ_BDL;
  float2* Qb = p;  p += (size_t)mcount*SZ_BDL;
  float2* Kb = p;  p += (size_t)mcount*SZ_BDL;
  float2* Vb = p;  p += (size_t)mcount*SZ_BDL;
  float2* Xc = p;  p += SZ_X;
  float2* ybuf = p; p += (size_t)Bn*2*Dn;
  float2* gbuf = p; p += (size_t)Bn*2*Dn;

  ushort* us = (ushort*)p;
  auto grab = [&](size_t n){ ushort* r = us; us += n; return r; };
  ushort *AtRe[4], *AtIm[4];
  for (int i = 0; i < 4; ++i){ AtRe[i] = grab(NAt); AtIm[i] = grab(NAt); }
  ushort *WRe4[4], *WIm4[4];
  for (int f = 0; f < 4; ++f){ WRe4[f] = grab(8*(size_t)65536); WIm4[f] = grab(8*(size_t)65536); }
  ushort* ScRe = grab(2*(size_t)Dn*768);
  ushort* ScIm = grab(2*(size_t)Dn*768);
  ushort* XRe = grab((size_t)Bn*Dn*XP);
  ushort* XIm = grab((size_t)Bn*Dn*XP);
  ushort* ObRe = grab((size_t)mcount*NAt);
  ushort* ObIm = grab((size_t)mcount*NAt);

  float2* out0 = (float2*)d_out;                   // [B, 512, 1024]
  float2* out1 = out0 + (size_t)Bn*2*Dn*L4n;

  head_conv_kernel<<<(Bn*Dn*Ln)/256, 256, 0, stream>>>(X1, head_w, head_b, A);
  head_conv_kernel<<<(Bn*Dn*Ln)/256, 256, 0, stream>>>(
      X2, head_w + (size_t)Dn*CINn*KWn, head_b + Dn, Bc);

  fft_rows_kernel<256,8><<<Bn*Dn, 256, 0, stream>>>(A,  iA, 256,0,256,0, 1.0f, 1.0f/256.0f);
  fft_rows_kernel<256,8><<<Bn*Dn, 256, 0, stream>>>(Bc, iB, 256,0,256,0, 1.0f, 1.0f/256.0f);

  // pack bf16 operands
  pack_at<<<512, 256, 0, stream>>>(A,  AtRe[0], AtIm[0]);
  pack_at<<<512, 256, 0, stream>>>(Bc, AtRe[1], AtIm[1]);
  pack_at<<<512, 256, 0, stream>>>(iA, AtRe[2], AtIm[2]);
  pack_at<<<512, 256, 0, stream>>>(iB, AtRe[3], AtIm[3]);
  pack_w<<<dim3(2048, 4), 256, 0, stream>>>(wq, wk, wv, wo,
      WRe4[0], WIm4[0], WRe4[1], WIm4[1], WRe4[2], WIm4[2], WRe4[3], WIm4[3]);
  pack_sc<<<1536, 256, 0, stream>>>(sc, ScRe, ScIm);

  auto run_ssca = [&](int ia, int ib, int set, float2* dstbase){
    for (int m0 = 0; m0 < 4; m0 += mcount){
      qkv_mfma<<<dim3(Bn*16, 3*mcount), 256, 0, stream>>>(
          AtRe[ia], AtIm[ia], AtRe[ib], AtIm[ib],
          WRe4[0], WIm4[0], WRe4[1], WIm4[1], WRe4[2], WIm4[2],
          Qb, Kb, Vb, set, m0, SZ_BDL);
      attn_fused_kernel<<<dim3(Bn*Hn*16, mcount), 256, 0, stream>>>(
          Qb, Kb, Vb, ObRe, ObIm, SZ_BDL, NAt);
      wo_mfma<<<dim3(Bn*16, mcount), 256, 0, stream>>>(
          ObRe, ObIm, WRe4[3], WIm4[3], Xc, set, m0);
    }
    row_mean_kernel<<<Bn*Dn, 256, 0, stream>>>(Xc, ybuf);
    eca_gate_kernel<<<(Bn*Dn + 255)/256, 256, 0, stream>>>(ybuf, se + set*KEn, gbuf, Dn);
    eca_apply_pack<<<(int)(SZ_X/256), 256, 0, stream>>>(Xc, gbuf, XRe, XIm);
    conv_mfma<<<Bn*64, 256, 0, stream>>>(
        ScRe + (size_t)set*Dn*768, ScIm + (size_t)set*Dn*768, XRe, XIm, dstbase, 2*Dn);
  };

  run_ssca(0, 1, 0, out0);   // R  -> out0 channels [0,256)
  run_ssca(2, 3, 1, out1);   // kk -> out1 channels [0,256)

  // R2[:,256:] = fft(kk) ; k2[:,256:] = ifft(R)
  fft_rows_kernel<1024,10><<<Bn*Dn, 256, 0, stream>>>(out1, out0, 2*Dn,0, 2*Dn,Dn, -1.0f, 1.0f);
  fft_rows_kernel<1024,10><<<Bn*Dn, 256, 0, stream>>>(out0, out1, 2*Dn,0, 2*Dn,Dn, 1.0f, 1.0f/1024.0f);

  for (int t = 0; t < 2; ++t){
    float2* op = (t == 0) ? out0 : out1;
    row_mean_kernel<<<Bn*2*Dn, 256, 0, stream>>>(op, ybuf);
    eca_gate_kernel<<<(Bn*2*Dn + 255)/256, 256, 0, stream>>>(ybuf, te + t*KEn, gbuf, 2*Dn);
    eca_apply_kernel<<<(Bn*2*Dn*L4n)/256, 256, 0, stream>>>(op, gbuf);
  }
}

// Round 7
// 437.478 us; speedup vs baseline: 10.4465x; 1.5327x over previous
//
#include <hip/hip_runtime.h>
#include <math.h>

namespace {

constexpr int Bn = 8, CINn = 16, Ln = 256, Dn = 256, Hn = 8, DKn = 32, DVn = 32;
constexpr int KWn = 3, KEn = 5, L4n = 1024;
constexpr float EPSf = 1e-9f;
constexpr int XP = 1040;   // bf16 X-plane pitch (8-col halo each side)
constexpr int LP = 40;     // LDS pitch in ushorts for 32-k chunk

typedef __attribute__((ext_vector_type(8))) short short8b;
typedef __attribute__((ext_vector_type(4))) float f32x4;

__device__ __forceinline__ float2 cmul(float2 a, float2 b){
  return make_float2(a.x*b.x - a.y*b.y, a.x*b.y + a.y*b.x);
}
__device__ __forceinline__ float2 cfma(float2 a, float2 b, float2 c){
  c.x = fmaf(a.x, b.x, c.x); c.x = fmaf(-a.y, b.y, c.x);
  c.y = fmaf(a.x, b.y, c.y); c.y = fmaf(a.y, b.x, c.y);
  return c;
}
__device__ __forceinline__ ushort f2bf(float f){
  uint u = __float_as_uint(f);
  u += 0x7fffu + ((u >> 16) & 1u);   // RNE
  return (ushort)(u >> 16);
}
__device__ __forceinline__ short8b neg8(short8b v){
  union { short8b s; uint u[4]; } x; x.s = v;
  #pragma unroll
  for (int i = 0; i < 4; ++i) x.u[i] ^= 0x80008000u;
  return x.s;
}

// A[b,o,l] = sum_c sum_i X[b,c,l+i-1] * hw[o,c,i] + hb[o]
__global__ void head_conv_kernel(const float2* __restrict__ X, const float2* __restrict__ hw,
                                 const float2* __restrict__ hb, float2* __restrict__ out){
  int idx = blockIdx.x * blockDim.x + threadIdx.x;
  if (idx >= Bn*Dn*Ln) return;
  int l = idx & (Ln-1);
  int o = (idx >> 8) & (Dn-1);
  int b = idx >> 16;
  float2 acc = hb[o];
  for (int c = 0; c < CINn; ++c){
    const float2* xr = X + (size_t)(b*CINn + c)*Ln;
    const float2* wr = hw + (size_t)(o*CINn + c)*KWn;
    #pragma unroll
    for (int i = 0; i < KWn; ++i){
      int ll = l + i - 1;
      if (ll >= 0 && ll < Ln) acc = cfma(xr[ll], wr[i], acc);
    }
  }
  out[idx] = acc;
}

// In-LDS radix-2 FFT with twiddle table; rows mapped through (chans, coff).
template<int N, int LOG>
__global__ void fft_rows_kernel(const float2* __restrict__ src0, float2* __restrict__ dst0,
                                int schans, int scoff, int dchans, int dcoff,
                                float sign, float scale){
  __shared__ float2 buf[N];
  __shared__ float2 tw[N/2];
  int row = blockIdx.x;
  int rb = row >> 8, rc = row & 255;
  const float2* src = src0 + (size_t)(rb*schans + scoff + rc)*N;
  float2* dst = dst0 + (size_t)(rb*dchans + dcoff + rc)*N;
  int tid = threadIdx.x;
  for (int i = tid; i < N/2; i += 256){
    float a = sign * 6.2831853071795864f * (float)i / (float)N;
    float s, c; __sincosf(a, &s, &c);
    tw[i] = make_float2(c, s);
  }
  for (int i = tid; i < N; i += 256){
    unsigned r = __brev((unsigned)i) >> (32 - LOG);
    buf[r] = src[i];
  }
  __syncthreads();
  for (int st = 1; st <= LOG; ++st){
    int half = 1 << (st-1);
    for (int bf = tid; bf < N/2; bf += 256){
      int blk = bf >> (st-1);
      int pos = bf & (half-1);
      int i0 = (blk << st) + pos;
      int i1 = i0 + half;
      float2 w = tw[pos << (LOG-st)];
      float2 u = buf[i0];
      float2 t = cmul(w, buf[i1]);
      buf[i0] = make_float2(u.x + t.x, u.y + t.y);
      buf[i1] = make_float2(u.x - t.x, u.y - t.y);
    }
    __syncthreads();
  }
  for (int i = tid; i < N; i += 256)
    dst[i] = make_float2(buf[i].x * scale, buf[i].y * scale);
}

// ---------------- unified complex bf16 MFMA GEMM core ----------------
// C[m,n] = sum_k A[m,k]*B[k,n] (complex), A/B bf16 re/im planes.
// Block tile 64m x 64n, K-chunk 32, 4 waves (2x2 of 32x32 wave tiles).
// conv!=0: B row k -> Xplane row c=k/3, col 8+n0+nn+(k%3)-1.
// cmode 0: out[m*crow+n]; cmode 1: out[n*crow+m] via LDS transpose.
// ore/oim non-null -> write bf16 planes instead of float2 cbase.
__device__ __forceinline__ void cgemm_core(
    const ushort* __restrict__ Are, const ushort* __restrict__ Aim, int pitchA, int am0,
    const ushort* __restrict__ Bre, const ushort* __restrict__ Bim, int pitchB, int n0,
    int K, int conv, float2* __restrict__ cbase, size_t crow, int cmode,
    ushort* __restrict__ ore, ushort* __restrict__ oim)
{
  __shared__ ushort sh[10240];
  ushort* As_re = sh;
  ushort* As_im = sh + 2560;
  ushort* Bs_re = sh + 5120;
  ushort* Bs_im = sh + 7680;
  int tid = threadIdx.x;
  int lane = tid & 63, w = tid >> 6;
  int wm = w >> 1, wn = w & 1;
  int lrow = lane & 15, lhalf = lane >> 4;
  f32x4 ar[2][2], ai[2][2];
  #pragma unroll
  for (int s = 0; s < 2; ++s)
    #pragma unroll
    for (int t = 0; t < 2; ++t){ ar[s][t] = (f32x4){0,0,0,0}; ai[s][t] = (f32x4){0,0,0,0}; }
  int nk = K >> 5;
  for (int kc = 0; kc < nk; ++kc){
    int k0 = kc << 5;
    __syncthreads();
    #pragma unroll
    for (int rep = 0; rep < 2; ++rep){
      int q = tid + rep*256;
      int row = q >> 3, kq = (q & 7)*4;
      size_t go = (size_t)(am0 + row)*pitchA + k0 + kq;
      *(uint2*)&As_re[row*LP + kq] = *(const uint2*)&Are[go];
      *(uint2*)&As_im[row*LP + kq] = *(const uint2*)&Aim[go];
    }
    if (!conv){
      #pragma unroll
      for (int rep = 0; rep < 2; ++rep){
        int q = tid + rep*256;
        int k = q >> 4, nq = (q & 15)*4;
        size_t go = (size_t)(k0 + k)*pitchB + n0 + nq;
        uint2 vr = *(const uint2*)&Bre[go];
        uint2 vi = *(const uint2*)&Bim[go];
        ushort* dr = &Bs_re[nq*LP + k];
        ushort* di = &Bs_im[nq*LP + k];
        dr[0]    = (ushort)(vr.x);      di[0]    = (ushort)(vi.x);
        dr[LP]   = (ushort)(vr.x>>16);  di[LP]   = (ushort)(vi.x>>16);
        dr[2*LP] = (ushort)(vr.y);      di[2*LP] = (ushort)(vi.y);
        dr[3*LP] = (ushort)(vr.y>>16);  di[3*LP] = (ushort)(vi.y>>16);
      }
    } else {
      #pragma unroll
      for (int rep = 0; rep < 8; ++rep){
        int idx = tid + rep*256;
        int k = idx >> 6, nn = idx & 63;
        uint kk = (uint)(k0 + k);
        uint c = (kk * 0xAAABu) >> 17;
        int i = (int)(kk - c*3u);
        size_t go = (size_t)c*XP + 8 + n0 + nn + i - 1;
        Bs_re[nn*LP + k] = Bre[go];
        Bs_im[nn*LP + k] = Bim[go];
      }
    }
    __syncthreads();
    short8b afr[2], afi[2], bfr[2], bfi[2];
    #pragma unroll
    for (int s = 0; s < 2; ++s){
      int row = wm*32 + s*16 + lrow;
      afr[s] = *(const short8b*)&As_re[row*LP + lhalf*8];
      afi[s] = *(const short8b*)&As_im[row*LP + lhalf*8];
    }
    #pragma unroll
    for (int t = 0; t < 2; ++t){
      int row = wn*32 + t*16 + lrow;
      bfr[t] = *(const short8b*)&Bs_re[row*LP + lhalf*8];
      bfi[t] = *(const short8b*)&Bs_im[row*LP + lhalf*8];
    }
    #pragma unroll
    for (int s = 0; s < 2; ++s){
      short8b ain = neg8(afi[s]);
      #pragma unroll
      for (int t = 0; t < 2; ++t){
        ar[s][t] = __builtin_amdgcn_mfma_f32_16x16x32_bf16(ain,    bfi[t], ar[s][t], 0, 0, 0);
        ar[s][t] = __builtin_amdgcn_mfma_f32_16x16x32_bf16(afr[s], bfr[t], ar[s][t], 0, 0, 0);
        ai[s][t] = __builtin_amdgcn_mfma_f32_16x16x32_bf16(afi[s], bfr[t], ai[s][t], 0, 0, 0);
        ai[s][t] = __builtin_amdgcn_mfma_f32_16x16x32_bf16(afr[s], bfi[t], ai[s][t], 0, 0, 0);
      }
    }
  }
  if (cmode == 0){
    #pragma unroll
    for (int s = 0; s < 2; ++s)
      #pragma unroll
      for (int t = 0; t < 2; ++t)
        #pragma unroll
        for (int r = 0; r < 4; ++r){
          int mm = wm*32 + s*16 + lhalf*4 + r;
          int nn = wn*32 + t*16 + lrow;
          if (ore){
            ore[(size_t)mm*crow + nn] = f2bf(ar[s][t][r]);
            oim[(size_t)mm*crow + nn] = f2bf(ai[s][t][r]);
          } else {
            cbase[(size_t)mm*crow + nn] = make_float2(ar[s][t][r], ai[s][t][r]);
          }
        }
  } else {
    float2* T = (float2*)sh;               // [64][33] float2
    #pragma unroll
    for (int h2 = 0; h2 < 2; ++h2){
      __syncthreads();
      if (wn == h2){
        #pragma unroll
        for (int s = 0; s < 2; ++s)
          #pragma unroll
          for (int t = 0; t < 2; ++t)
            #pragma unroll
            for (int r = 0; r < 4; ++r){
              int mm = wm*32 + s*16 + lhalf*4 + r;
              int nn = t*16 + lrow;
              T[mm*33 + nn] = make_float2(ar[s][t][r], ai[s][t][r]);
            }
      }
      __syncthreads();
      #pragma unroll
      for (int rep = 0; rep < 8; ++rep){
        int idx = tid + rep*256;
        int mm = idx & 63, nn = idx >> 6;  // nn 0..31
        float2 v = T[mm*33 + nn];
        if (ore){
          ore[(size_t)(h2*32 + nn)*crow + mm] = f2bf(v.x);
          oim[(size_t)(h2*32 + nn)*crow + mm] = f2bf(v.y);
        } else {
          cbase[(size_t)(h2*32 + nn)*crow + mm] = v;
        }
      }
    }
  }
}

// ---------------- GEMM wrappers ----------------
// Q,K -> bf16 planes [b][l][e]; V -> bf16 plane [b][e][l] (transposed).
__global__ __launch_bounds__(256) void qkv_mfma(
    const ushort* __restrict__ aAre, const ushort* __restrict__ aAim,
    const ushort* __restrict__ aBre, const ushort* __restrict__ aBim,
    const ushort* __restrict__ WqRe, const ushort* __restrict__ WqIm,
    const ushort* __restrict__ WkRe, const ushort* __restrict__ WkIm,
    const ushort* __restrict__ WvRe, const ushort* __restrict__ WvIm,
    ushort* __restrict__ QpRe, ushort* __restrict__ QpIm,
    ushort* __restrict__ KpRe, ushort* __restrict__ KpIm,
    ushort* __restrict__ VpRe, ushort* __restrict__ VpIm,
    int set, int m0, size_t pstride)
{
  int my = blockIdx.y;
  int ml = my / 3, which = my - ml*3;
  int m = m0 + ml;
  bool useA = (which == 0) ? (m == 0 || m == 2) : (m == 0 || m == 3);
  const ushort* Are = useA ? aAre : aBre;
  const ushort* Aim = useA ? aAim : aBim;
  const ushort* WRe = (which == 0) ? WqRe : (which == 1) ? WkRe : WvRe;
  const ushort* WIm = (which == 0) ? WqIm : (which == 1) ? WkIm : WvIm;
  size_t woff = (size_t)(set*4 + m)*Dn*Dn;
  int bx = blockIdx.x;
  int nt = bx & 3, mt = (bx >> 2) & 3, b = bx >> 4;
  int l0 = mt*64, e0 = nt*64;
  const ushort* ARe = Are + (size_t)b*Ln*Dn;
  const ushort* AIm = Aim + (size_t)b*Ln*Dn;
  size_t po = (size_t)ml*pstride;
  if (which == 2){
    ushort* orp = VpRe + po + ((size_t)b*Dn + e0)*Ln + l0;
    ushort* oip = VpIm + po + ((size_t)b*Dn + e0)*Ln + l0;
    cgemm_core(ARe, AIm, Dn, l0, WRe + woff, WIm + woff, Dn, e0, Dn, 0,
               nullptr, Ln, 1, orp, oip);
  } else {
    ushort* orp = ((which == 0) ? QpRe : KpRe) + po + ((size_t)b*Ln + l0)*Dn + e0;
    ushort* oip = ((which == 0) ? QpIm : KpIm) + po + ((size_t)b*Ln + l0)*Dn + e0;
    cgemm_core(ARe, AIm, Dn, l0, WRe + woff, WIm + woff, Dn, e0, Dn, 0,
               nullptr, Dn, 0, orp, oip);
  }
}

__global__ __launch_bounds__(256) void wo_mfma(
    const ushort* __restrict__ ORe, const ushort* __restrict__ OIm,
    const ushort* __restrict__ WoRe, const ushort* __restrict__ WoIm,
    float2* __restrict__ Xc, int set, int m0)
{
  int ml = blockIdx.y;
  int m = m0 + ml;
  size_t woff = (size_t)(set*4 + m)*Dn*Dn;
  int bx = blockIdx.x;
  int nt = bx & 3, mt = (bx >> 2) & 3, b = bx >> 4;
  int l0 = mt*64, d0 = nt*64;
  const ushort* ARe = ORe + ((size_t)ml*Bn + b)*Ln*Dn;
  const ushort* AIm = OIm + ((size_t)ml*Bn + b)*Ln*Dn;
  float2* cb = Xc + ((size_t)b*Dn + d0)*L4n + m*Ln + l0;
  cgemm_core(ARe, AIm, Dn, l0, WoRe + woff, WoIm + woff, Dn, d0, Dn, 0,
             cb, L4n, 1, nullptr, nullptr);
}

__global__ __launch_bounds__(256) void conv_mfma(
    const ushort* __restrict__ WRe, const ushort* __restrict__ WIm,
    const ushort* __restrict__ XRe, const ushort* __restrict__ XIm,
    float2* __restrict__ out, int ochans)
{
  int bx = blockIdx.x;
  int xt = bx & 15, ot = (bx >> 4) & 3, b = bx >> 6;
  int o0 = ot*64, x0 = xt*64;
  const ushort* xr = XRe + (size_t)b*Dn*XP;
  const ushort* xi = XIm + (size_t)b*Dn*XP;
  float2* cb = out + ((size_t)(b*ochans) + o0)*L4n + x0;
  cgemm_core(WRe, WIm, 768, o0, xr, xi, XP, x0, 768, 1, cb, L4n, 0,
             nullptr, nullptr);
}

// ---------------- MFMA attention ----------------
// Block = (b, h, 16-q tile), qt in HIGH bits of blockIdx.x (XCD L2 reuse).
// Wave w owns k-range [w*64, w*64+64). Q/K/V fragments read directly from
// global bf16 planes (16B dwordx4, frag layout == plane rows). Scores in f32
// accumulators; magminmax via shfl + tiny LDS; P bf16 in LDS; PV via MFMA;
// cross-wave sum via LDS; bf16 O planes out.
__global__ __launch_bounds__(256) void attn_mfma(
    const ushort* __restrict__ QRe, const ushort* __restrict__ QIm,
    const ushort* __restrict__ KRe, const ushort* __restrict__ KIm,
    const ushort* __restrict__ VRe, const ushort* __restrict__ VIm,
    ushort* __restrict__ ORe, ushort* __restrict__ OIm, size_t pstride)
{
  size_t po = (size_t)blockIdx.y*pstride;
  const ushort* qre = QRe + po; const ushort* qim = QIm + po;
  const ushort* kre = KRe + po; const ushort* kim = KIm + po;
  const ushort* vre = VRe + po; const ushort* vim = VIm + po;
  ushort* ore = ORe + po; ushort* oim = OIm + po;
  int bx = blockIdx.x;
  int qt = bx >> 6, h = (bx >> 3) & 7, b = bx & 7;
  int q0 = qt*16;
  int tid = threadIdx.x;
  int lane = tid & 63, w = tid >> 6;
  int lg = lane >> 4, lr = lane & 15;
  __shared__ ushort PsRe[16*264];
  __shared__ ushort PsIm[16*264];
  __shared__ float2 mmb[4][4][4];        // [wave][lanegroup][r] = (mn,mx)
  __shared__ float2 red[4][16][32];      // cross-wave PV partials
  const float scl = 0.17677669529663687f;   // 1/sqrt(32)

  // Q A-fragment: rows q0+lr, k-dim d = lg*8..+7
  size_t qoff = ((size_t)(b*Ln + q0 + lr))*Dn + h*DKn + lg*8;
  short8b aqr = *(const short8b*)&qre[qoff];
  short8b aqi = *(const short8b*)&qim[qoff];
  short8b aqin = neg8(aqi);

  // QK^T: wave's 4 n-tiles of 16 k each
  f32x4 sr[4], si[4];
  #pragma unroll
  for (int t = 0; t < 4; ++t){ sr[t] = (f32x4){0,0,0,0}; si[t] = (f32x4){0,0,0,0}; }
  #pragma unroll
  for (int t = 0; t < 4; ++t){
    int kcol = w*64 + t*16 + lr;
    size_t koff = ((size_t)(b*Ln + kcol))*Dn + h*DKn + lg*8;
    short8b bkr = *(const short8b*)&kre[koff];
    short8b bki = *(const short8b*)&kim[koff];
    sr[t] = __builtin_amdgcn_mfma_f32_16x16x32_bf16(aqin, bki, sr[t], 0, 0, 0);
    sr[t] = __builtin_amdgcn_mfma_f32_16x16x32_bf16(aqr,  bkr, sr[t], 0, 0, 0);
    si[t] = __builtin_amdgcn_mfma_f32_16x16x32_bf16(aqi,  bkr, si[t], 0, 0, 0);
    si[t] = __builtin_amdgcn_mfma_f32_16x16x32_bf16(aqr,  bki, si[t], 0, 0, 0);
  }
  // scale + magnitudes + per-row (q = lg*4+r) min/max over wave's 64 k
  float mag[4][4];
  float mnr[4], mxr[4];
  #pragma unroll
  for (int r = 0; r < 4; ++r){ mnr[r] = 3.4e38f; mxr[r] = 0.f; }
  #pragma unroll
  for (int t = 0; t < 4; ++t)
    #pragma unroll
    for (int r = 0; r < 4; ++r){
      float x = sr[t][r]*scl, y = si[t][r]*scl;
      sr[t][r] = x; si[t][r] = y;
      float m = sqrtf(x*x + y*y);
      mag[t][r] = m;
      mnr[r] = fminf(mnr[r], m); mxr[r] = fmaxf(mxr[r], m);
    }
  #pragma unroll
  for (int off = 1; off < 16; off <<= 1)
    #pragma unroll
    for (int r = 0; r < 4; ++r){
      mnr[r] = fminf(mnr[r], __shfl_xor(mnr[r], off));
      mxr[r] = fmaxf(mxr[r], __shfl_xor(mxr[r], off));
    }
  if (lr == 0){
    #pragma unroll
    for (int r = 0; r < 4; ++r) mmb[w][lg][r] = make_float2(mnr[r], mxr[r]);
  }
  __syncthreads();
  float fmn[4], fmx[4];
  #pragma unroll
  for (int r = 0; r < 4; ++r){
    float2 v0 = mmb[0][lg][r], v1 = mmb[1][lg][r];
    float2 v2 = mmb[2][lg][r], v3 = mmb[3][lg][r];
    fmn[r] = fminf(fminf(v0.x, v1.x), fminf(v2.x, v3.x));
    fmx[r] = fmaxf(fmaxf(v0.y, v1.y), fmaxf(v2.y, v3.y));
  }
  // normalize own scores, write P (bf16) to LDS
  #pragma unroll
  for (int t = 0; t < 4; ++t)
    #pragma unroll
    for (int r = 0; r < 4; ++r){
      int q = lg*4 + r, k = w*64 + t*16 + lr;
      float m = mag[t][r];
      float f = ((m - fmn[r]) / (fmx[r] - fmn[r] + EPSf)) / (m + EPSf);
      PsRe[q*264 + k] = f2bf(sr[t][r]*f);
      PsIm[q*264 + k] = f2bf(si[t][r]*f);
    }
  __syncthreads();
  // PV: wave's 2 k-chunks of 32, 2 dv-tiles of 16
  f32x4 pr[2], pi[2];
  #pragma unroll
  for (int t = 0; t < 2; ++t){ pr[t] = (f32x4){0,0,0,0}; pi[t] = (f32x4){0,0,0,0}; }
  #pragma unroll
  for (int kc = 0; kc < 2; ++kc){
    int k0 = w*64 + kc*32;
    short8b par = *(const short8b*)&PsRe[lr*264 + k0 + lg*8];
    short8b pai = *(const short8b*)&PsIm[lr*264 + k0 + lg*8];
    short8b pain = neg8(pai);
    #pragma unroll
    for (int t = 0; t < 2; ++t){
      int dv = t*16 + lr;
      size_t voff = ((size_t)(b*Dn + h*DVn + dv))*Ln + k0 + lg*8;
      short8b bvr = *(const short8b*)&vre[voff];
      short8b bvi = *(const short8b*)&vim[voff];
      pr[t] = __builtin_amdgcn_mfma_f32_16x16x32_bf16(pain, bvi, pr[t], 0, 0, 0);
      pr[t] = __builtin_amdgcn_mfma_f32_16x16x32_bf16(par,  bvr, pr[t], 0, 0, 0);
      pi[t] = __builtin_amdgcn_mfma_f32_16x16x32_bf16(pai,  bvr, pi[t], 0, 0, 0);
      pi[t] = __builtin_amdgcn_mfma_f32_16x16x32_bf16(par,  bvi, pi[t], 0, 0, 0);
    }
  }
  #pragma unroll
  for (int t = 0; t < 2; ++t)
    #pragma unroll
    for (int r = 0; r < 4; ++r)
      red[w][lg*4 + r][t*16 + lr] = make_float2(pr[t][r], pi[t][r]);
  __syncthreads();
  #pragma unroll
  for (int rep = 0; rep < 2; ++rep){
    int idx = tid + rep*256;
    int q = idx >> 5, dv = idx & 31;
    float2 s0 = red[0][q][dv], s1 = red[1][q][dv];
    float2 s2 = red[2][q][dv], s3 = red[3][q][dv];
    float sx = s0.x + s1.x + s2.x + s3.x;
    float sy = s0.y + s1.y + s2.y + s3.y;
    size_t oo = ((size_t)(b*Ln + q0 + q))*Dn + h*DVn + dv;
    ore[oo] = f2bf(sx); oim[oo] = f2bf(sy);
  }
}

// ---------------- pack kernels ----------------
__global__ void pack_at(const float2* __restrict__ in, ushort* __restrict__ ore,
                        ushort* __restrict__ oim){
  __shared__ float2 T[32][33];
  int bx = blockIdx.x;
  int lt = bx & 7, dt = (bx >> 3) & 7, b = bx >> 6;
  int tid = threadIdx.x;
  int c = tid & 31, rr = tid >> 5;
  #pragma unroll
  for (int it = 0; it < 4; ++it){
    int d = rr + it*8;
    T[d][c] = in[((size_t)b*Dn + dt*32 + d)*Ln + lt*32 + c];
  }
  __syncthreads();
  #pragma unroll
  for (int it = 0; it < 4; ++it){
    int l = rr + it*8;
    float2 v = T[c][l];
    size_t o = ((size_t)b*Ln + lt*32 + l)*Dn + dt*32 + c;
    ore[o] = f2bf(v.x); oim[o] = f2bf(v.y);
  }
}

__global__ void pack_w(const float2* __restrict__ wq, const float2* __restrict__ wk,
                       const float2* __restrict__ wv, const float2* __restrict__ wo,
                       ushort* r0, ushort* i0, ushort* r1, ushort* i1,
                       ushort* r2, ushort* i2, ushort* r3, ushort* i3){
  int f = blockIdx.y;
  const float2* in = (f == 0) ? wq : (f == 1) ? wk : (f == 2) ? wv : wo;
  ushort* orr = (f == 0) ? r0 : (f == 1) ? r1 : (f == 2) ? r2 : r3;
  ushort* oii = (f == 0) ? i0 : (f == 1) ? i1 : (f == 2) ? i2 : i3;
  size_t idx = (size_t)blockIdx.x*256 + threadIdx.x;
  float2 v = in[idx];
  orr[idx] = f2bf(v.x); oii[idx] = f2bf(v.y);
}

__global__ void pack_sc(const float2* __restrict__ sc, ushort* __restrict__ ore,
                        ushort* __restrict__ oim){
  size_t idx = (size_t)blockIdx.x*256 + threadIdx.x;
  float2 v = sc[idx];
  ore[idx] = f2bf(v.x); oim[idx] = f2bf(v.y);
}

__global__ void eca_apply_pack(const float2* __restrict__ X, const float2* __restrict__ g,
                               ushort* __restrict__ xre, ushort* __restrict__ xim){
  int idx = blockIdx.x*256 + threadIdx.x;
  int row = idx >> 10, x = idx & 1023;
  float2 v = cmul(X[idx], g[row]);
  size_t o = (size_t)row*XP + 8 + x;
  xre[o] = f2bf(v.x); xim[o] = f2bf(v.y);
  if (x < 8){ size_t o2 = (size_t)row*XP + x; xre[o2] = 0; xim[o2] = 0; }
  if (x >= 1016){ size_t o2 = (size_t)row*XP + x + 16; xre[o2] = 0; xim[o2] = 0; }
}

// mean over last dim (1024), one block per row
__global__ void row_mean_kernel(const float2* __restrict__ X, float2* __restrict__ y){
  int row = blockIdx.x;
  int tid = threadIdx.x;
  float sx = 0.f, sy = 0.f;
  const float2* xr = X + (size_t)row*L4n;
  for (int i = tid; i < L4n; i += 256){ float2 v = xr[i]; sx += v.x; sy += v.y; }
  __shared__ float rx[256], ry[256];
  rx[tid] = sx; ry[tid] = sy; __syncthreads();
  for (int st = 128; st > 0; st >>= 1){
    if (tid < st){ rx[tid] += rx[tid+st]; ry[tid] += ry[tid+st]; }
    __syncthreads();
  }
  if (tid == 0) y[row] = make_float2(rx[0]*(1.f/L4n), ry[0]*(1.f/L4n));
}

__global__ void eca_gate_kernel(const float2* __restrict__ y, const float2* __restrict__ w,
                                float2* __restrict__ g, int C){
  int idx = blockIdx.x*blockDim.x + threadIdx.x;
  if (idx >= Bn*C) return;
  int c = idx % C;
  int b = idx / C;
  float2 z = make_float2(0.f, 0.f);
  #pragma unroll
  for (int i = 0; i < KEn; ++i){
    int cc = c + i - 2;
    if (cc >= 0 && cc < C) z = cfma(w[i], y[b*C + cc], z);
  }
  g[idx] = make_float2(1.f/(1.f + expf(-z.x)), 1.f/(1.f + expf(-z.y)));
}

__global__ void eca_apply_kernel(float2* __restrict__ X, const float2* __restrict__ g){
  int idx = blockIdx.x*256 + threadIdx.x;
  int row = idx >> 10;
  X[idx] = cmul(X[idx], g[row]);
}

} // namespace

extern "C" void kernel_launch(void* const* d_in, const int* in_sizes, int n_in,
                              void* d_out, int out_size, void* d_ws, size_t ws_size,
                              hipStream_t stream){
  const float2* X1 = (const float2*)d_in[0];
  const float2* X2 = (const float2*)d_in[1];
  const float2* head_w = (const float2*)d_in[2];
  const float2* head_b = (const float2*)d_in[3];
  const float2* wq = (const float2*)d_in[4];
  const float2* wk = (const float2*)d_in[5];
  const float2* wv = (const float2*)d_in[6];
  const float2* wo = (const float2*)d_in[7];
  const float2* se = (const float2*)d_in[8];
  const float2* sc = (const float2*)d_in[9];
  const float2* te = (const float2*)d_in[10];

  const size_t SZ_BDL = (size_t)Bn*Dn*Ln;      // 524288 complex = 4 MB
  const size_t SZ_X   = (size_t)Bn*Dn*L4n;     // 16 MB
  const size_t small  = 2*(size_t)Bn*2*Dn;
  const size_t NAt    = (size_t)Bn*Ln*Dn;      // ushorts per plane

  const size_t US_FIX = 2*(4*NAt)               // At planes
                      + 2*(4*8*(size_t)65536)   // W planes
                      + 2*(2*(size_t)Dn*768)    // sc planes
                      + 2*((size_t)Bn*Dn*XP);   // X planes
  auto need_bytes = [&](int mc){
    return ((size_t)4*SZ_BDL + SZ_X + small)*sizeof(float2)
         + (US_FIX + (size_t)8*mc*NAt)*sizeof(ushort);   // Q,K,V,O x re,im
  };
  int mcount = 1;
  if (ws_size >= need_bytes(4)) mcount = 4;
  else if (ws_size >= need_bytes(2)) mcount = 2;

  float2* p = (float2*)d_ws;
  float2* A  = p;  p += SZ_BDL;
  float2* Bc = p;  p += SZ_BDL;
  float2* iA = p;  p += SZ_BDL;
  float2* iB = p;  p += SZ_BDL;
  float2* Xc = p;  p += SZ_X;
  float2* ybuf = p; p += (size_t)Bn*2*Dn;
  float2* gbuf = p; p += (size_t)Bn*2*Dn;

  ushort* us = (ushort*)p;
  auto grab = [&](size_t n){ ushort* r = us; us += n; return r; };
  ushort *AtRe[4], *AtIm[4];
  for (int i = 0; i < 4; ++i){ AtRe[i] = grab(NAt); AtIm[i] = grab(NAt); }
  ushort *WRe4[4], *WIm4[4];
  for (int f = 0; f < 4; ++f){ WRe4[f] = grab(8*(size_t)65536); WIm4[f] = grab(8*(size_t)65536); }
  ushort* ScRe = grab(2*(size_t)Dn*768);
  ushort* ScIm = grab(2*(size_t)Dn*768);
  ushort* XRe = grab((size_t)Bn*Dn*XP);
  ushort* XIm = grab((size_t)Bn*Dn*XP);
  ushort* QpRe = grab((size_t)mcount*NAt);
  ushort* QpIm = grab((size_t)mcount*NAt);
  ushort* KpRe = grab((size_t)mcount*NAt);
  ushort* KpIm = grab((size_t)mcount*NAt);
  ushort* VpRe = grab((size_t)mcount*NAt);
  ushort* VpIm = grab((size_t)mcount*NAt);
  ushort* ObRe = grab((size_t)mcount*NAt);
  ushort* ObIm = grab((size_t)mcount*NAt);

  float2* out0 = (float2*)d_out;                   // [B, 512, 1024]
  float2* out1 = out0 + (size_t)Bn*2*Dn*L4n;

  head_conv_kernel<<<(Bn*Dn*Ln)/256, 256, 0, stream>>>(X1, head_w, head_b, A);
  head_conv_kernel<<<(Bn*Dn*Ln)/256, 256, 0, stream>>>(
      X2, head_w + (size_t)Dn*CINn*KWn, head_b + Dn, Bc);

  fft_rows_kernel<256,8><<<Bn*Dn, 256, 0, stream>>>(A,  iA, 256,0,256,0, 1.0f, 1.0f/256.0f);
  fft_rows_kernel<256,8><<<Bn*Dn, 256, 0, stream>>>(Bc, iB, 256,0,256,0, 1.0f, 1.0f/256.0f);

  pack_at<<<512, 256, 0, stream>>>(A,  AtRe[0], AtIm[0]);
  pack_at<<<512, 256, 0, stream>>>(Bc, AtRe[1], AtIm[1]);
  pack_at<<<512, 256, 0, stream>>>(iA, AtRe[2], AtIm[2]);
  pack_at<<<512, 256, 0, stream>>>(iB, AtRe[3], AtIm[3]);
  pack_w<<<dim3(2048, 4), 256, 0, stream>>>(wq, wk, wv, wo,
      WRe4[0], WIm4[0], WRe4[1], WIm4[1], WRe4[2], WIm4[2], WRe4[3], WIm4[3]);
  pack_sc<<<1536, 256, 0, stream>>>(sc, ScRe, ScIm);

  auto run_ssca = [&](int ia, int ib, int set, float2* dstbase){
    for (int m0 = 0; m0 < 4; m0 += mcount){
      qkv_mfma<<<dim3(Bn*16, 3*mcount), 256, 0, stream>>>(
          AtRe[ia], AtIm[ia], AtRe[ib], AtIm[ib],
          WRe4[0], WIm4[0], WRe4[1], WIm4[1], WRe4[2], WIm4[2],
          QpRe, QpIm, KpRe, KpIm, VpRe, VpIm, set, m0, NAt);
      attn_mfma<<<dim3(Bn*Hn*16, mcount), 256, 0, stream>>>(
          QpRe, QpIm, KpRe, KpIm, VpRe, VpIm, ObRe, ObIm, NAt);
      wo_mfma<<<dim3(Bn*16, mcount), 256, 0, stream>>>(
          ObRe, ObIm, WRe4[3], WIm4[3], Xc, set, m0);
    }
    row_mean_kernel<<<Bn*Dn, 256, 0, stream>>>(Xc, ybuf);
    eca_gate_kernel<<<(Bn*Dn + 255)/256, 256, 0, stream>>>(ybuf, se + set*KEn, gbuf, Dn);
    eca_apply_pack<<<(int)(SZ_X/256), 256, 0, stream>>>(Xc, gbuf, XRe, XIm);
    conv_mfma<<<Bn*64, 256, 0, stream>>>(
        ScRe + (size_t)set*Dn*768, ScIm + (size_t)set*Dn*768, XRe, XIm, dstbase, 2*Dn);
  };

  run_ssca(0, 1, 0, out0);   // R  -> out0 channels [0,256)
  run_ssca(2, 3, 1, out1);   // kk -> out1 channels [0,256)

  // R2[:,256:] = fft(kk) ; k2[:,256:] = ifft(R)
  fft_rows_kernel<1024,10><<<Bn*Dn, 256, 0, stream>>>(out1, out0, 2*Dn,0, 2*Dn,Dn, -1.0f, 1.0f);
  fft_rows_kernel<1024,10><<<Bn*Dn, 256, 0, stream>>>(out0, out1, 2*Dn,0, 2*Dn,Dn, 1.0f, 1.0f/1024.0f);

  for (int t = 0; t < 2; ++t){
    float2* op = (t == 0) ? out0 : out1;
    row_mean_kernel<<<Bn*2*Dn, 256, 0, stream>>>(op, ybuf);
    eca_gate_kernel<<<(Bn*2*Dn + 255)/256, 256, 0, stream>>>(ybuf, te + t*KEn, gbuf, 2*Dn);
    eca_apply_kernel<<<(Bn*2*Dn*L4n)/256, 256, 0, stream>>>(op, gbuf);
  }
}